// Round 13
// baseline (1763.376 us; speedup 1.0000x reference)
//
#include <hip/hip_runtime.h>
#include <hip/hip_bf16.h>
#include <hip/hip_fp16.h>
#include <cstdint>
#include <cstddef>

#define B_ 32
#define S_ 128
#define T_ 128
#define E_ 128
#define U_ 256
#define V_ 32000
#define G4 1024          // 4*U
#define TV 4096000       // T_*V_

typedef __attribute__((ext_vector_type(8))) short short8_t;   // 8 bf16
typedef __attribute__((ext_vector_type(8))) unsigned short ushort8_t;
typedef __attribute__((ext_vector_type(4))) float f32x4;
typedef __attribute__((ext_vector_type(4))) unsigned uint4v;
typedef unsigned long long u64;

static __device__ __forceinline__ unsigned short f2bf(float x) {
  union { float f; unsigned int u; } v; v.f = x;
  unsigned int r = (v.u + 0x7fffu + ((v.u >> 16) & 1u)) >> 16;
  return (unsigned short)r;
}
static __device__ __forceinline__ float bf2f(unsigned short u) {
  return __uint_as_float(((unsigned)u) << 16);
}
static __device__ __forceinline__ float sigmoidf_(float x) {
  return 1.0f / (1.0f + __expf(-x));
}
static __device__ __forceinline__ float tanhf_(float x) {
  float e = __expf(2.0f * x);
  return 1.0f - 2.0f / (e + 1.0f);
}

// ---- e5m2 (truncated fp16) encode ----
static __device__ __forceinline__ unsigned int f2e5(float x) {
  __half h = __float2half(x);
  __half_raw hr = *(__half_raw*)&h;
  unsigned int u = hr.x;
  unsigned int r = (u + 0x7Fu + ((u >> 8) & 1u)) >> 8;   // RNE to 8 bits
  return r & 0xFFu;
}

// ---- packed fp16 helpers ----
static __device__ __forceinline__ unsigned pk2(float a, float b) {
  auto h = __builtin_amdgcn_cvt_pkrtz(a, b);
  return __builtin_bit_cast(unsigned, h);
}
#define SEL01 0x05000400u   // bytes -> half2(b0<<8, b1<<8)
#define SEL23 0x07000600u
static __device__ __forceinline__ unsigned e5pair(unsigned w, unsigned sel) {
  return __builtin_amdgcn_perm(w, 0u, sel);
}
static __device__ __forceinline__ float dot2(unsigned a, unsigned b, float c) {
  float d;
  asm("v_dot2_f32_f16 %0, %1, %2, %3" : "=v"(d) : "v"(a), "v"(b), "v"(c));
  return d;
}
static __device__ __forceinline__ unsigned pkadd(unsigned a, unsigned b) {
  unsigned d; asm("v_pk_add_f16 %0, %1, %2" : "=v"(d) : "v"(a), "v"(b)); return d;
}
static __device__ __forceinline__ unsigned pkmul(unsigned a, unsigned b) {
  unsigned d; asm("v_pk_mul_f16 %0, %1, %2" : "=v"(d) : "v"(a), "v"(b)); return d;
}
static __device__ __forceinline__ unsigned pkfma(unsigned a, unsigned b, unsigned c) {
  unsigned d; asm("v_pk_fma_f16 %0, %1, %2, %3" : "=v"(d) : "v"(a), "v"(b), "v"(c)); return d;
}
static __device__ __forceinline__ unsigned pkmax(unsigned a, unsigned b) {
  unsigned d; asm("v_pk_max_f16 %0, %1, %2" : "=v"(d) : "v"(a), "v"(b)); return d;
}
static __device__ __forceinline__ unsigned pkmin(unsigned a, unsigned b) {
  unsigned d; asm("v_pk_min_f16 %0, %1, %2" : "=v"(d) : "v"(a), "v"(b)); return d;
}

// ---- tagged agent-scope publication ----
static __device__ __forceinline__ void pub64u(u64* p, unsigned val, unsigned tag) {
  u64 v = ((u64)tag << 32) | (u64)val;
  __hip_atomic_store(p, v, __ATOMIC_RELAXED, __HIP_MEMORY_SCOPE_AGENT);
}
static __device__ __forceinline__ u64 ld64(const u64* p) {
  return __hip_atomic_load(p, __ATOMIC_RELAXED, __HIP_MEMORY_SCOPE_AGENT);
}

// ---------------------------------------------------------------------------
// K1 (fused): blocks 0..1023 = embedding gather + x@Wx + bias;
//             blocks 1024..3023 = fc_W transpose -> bf16.
// ---------------------------------------------------------------------------
__global__ __launch_bounds__(256) void k_prep(
    const int* __restrict__ src, const int* __restrict__ tgt,
    const float* __restrict__ enc_emb, const float* __restrict__ enc_Wx,
    const float* __restrict__ enc_b,
    const float* __restrict__ dec_emb, const float* __restrict__ dec_Wx,
    const float* __restrict__ dec_b,
    float* __restrict__ Xe, float* __restrict__ Xd,
    const float* __restrict__ fcW, unsigned short* __restrict__ fcWt)
{
  __shared__ float shmem[64 * 65];
  int wg = blockIdx.x;
  int tid = threadIdx.x;

  if (wg >= 1024) {
    int bid = wg - 1024;
    int n0 = (bid % 500) * 64, k0 = (bid / 500) * 64;
    for (int i = 0; i < 16; ++i) {
      int lin = i * 256 + tid;
      int k = lin >> 6, n = lin & 63;
      shmem[k * 65 + n] = fcW[(size_t)(k0 + k) * V_ + n0 + n];
    }
    __syncthreads();
    for (int i = 0; i < 16; ++i) {
      int lin = i * 256 + tid;
      int n = lin >> 6, k = lin & 63;
      fcWt[(size_t)(n0 + n) * 256 + k0 + k] = f2bf(shmem[k * 65 + n]);
    }
    return;
  }

  bool is_dec = (wg >= 512);
  int r0 = (is_dec ? (wg - 512) : wg) * 8;
  const float* emb  = is_dec ? dec_emb : enc_emb;
  const float* W    = is_dec ? (dec_Wx + (size_t)U_ * G4) : enc_Wx;
  const float* bias = is_dec ? dec_b : enc_b;
  float* Xout = is_dec ? Xd : Xe;

  for (int i = 0; i < 4; ++i) {
    int lin = i * 256 + tid;
    int rr = lin >> 7, k = lin & 127;
    int r = r0 + rr;               // r = step*32 + b
    int b = r & 31, st = r >> 5;
    int tok;
    if (is_dec) tok = tgt[b * T_ + (st > 0 ? st - 1 : 0)];
    else        tok = src[b * S_ + st];
    shmem[rr * 128 + k] = emb[(size_t)tok * E_ + k];
  }
  __syncthreads();

  float acc[8][4];
  #pragma unroll
  for (int rr = 0; rr < 8; ++rr)
    #pragma unroll
    for (int cc = 0; cc < 4; ++cc) acc[rr][cc] = 0.f;

  for (int k = 0; k < E_; ++k) {
    float w0 = W[(size_t)k * G4 + tid];
    float w1 = W[(size_t)k * G4 + tid + 256];
    float w2 = W[(size_t)k * G4 + tid + 512];
    float w3 = W[(size_t)k * G4 + tid + 768];
    #pragma unroll
    for (int rr = 0; rr < 8; ++rr) {
      float e = shmem[rr * 128 + k];
      acc[rr][0] += e * w0; acc[rr][1] += e * w1;
      acc[rr][2] += e * w2; acc[rr][3] += e * w3;
    }
  }
  #pragma unroll
  for (int rr = 0; rr < 8; ++rr) {
    int r = r0 + rr;
    #pragma unroll
    for (int cc = 0; cc < 4; ++cc) {
      int col = tid + cc * 256;
      Xout[(size_t)r * G4 + col] = acc[rr][cc] + bias[col];
    }
  }
}

// ---------------------------------------------------------------------------
// K3: encoder LSTM, 8 WGs x 1024 threads per b (R10 verbatim).
// ---------------------------------------------------------------------------
__global__ __launch_bounds__(1024) void k_encoder8(
    const float* __restrict__ Xe, const float* __restrict__ Wh,
    float* __restrict__ enc_out, float* __restrict__ h_state,
    float* __restrict__ c_state, u64* __restrict__ hpubE /*[2][32][128]*/)
{
  __shared__ unsigned int WhU[64 * 128];
  __shared__ unsigned int h2[128];
  __shared__ float scr_z[8 * 128];

  int bid = blockIdx.x, tid = threadIdx.x;
  int b = bid & 31, g = bid >> 5;

  for (int idx = tid; idx < 64 * 128; idx += 1024) {
    int k4 = idx >> 7, c = idx & 127;
    int gc = (c >> 5) * 256 + g * 32 + (c & 31);
    unsigned w = 0;
    #pragma unroll
    for (int i = 0; i < 4; ++i)
      w |= f2e5(Wh[(size_t)(4 * k4 + i) * G4 + gc]) << (8 * i);
    WhU[k4 * 128 + c] = w;
  }
  if (tid < 128) h2[tid] = 0u;
  float c_reg = 0.f, h_reg = 0.f;
  __syncthreads();

  for (int s = 0; s < S_; ++s) {
    float xe0 = 0.f, xe1 = 0.f, xe2 = 0.f, xe3 = 0.f;
    if (tid < 32) {
      const float* xe = Xe + (size_t)(s * B_ + b) * G4 + g * 32 + tid;
      xe0 = xe[0]; xe1 = xe[256]; xe2 = xe[512]; xe3 = xe[768];
    }
    {
      int c = tid & 127, k8 = tid >> 7;
      const unsigned* wp = &WhU[(k8 * 8) * 128 + c];
      const unsigned* hh = &h2[k8 * 16];
      float z0 = 0.f, z1 = 0.f;
      #pragma unroll
      for (int j = 0; j < 8; ++j) {
        unsigned w = wp[j * 128];
        z0 = dot2(e5pair(w, SEL01), hh[2 * j], z0);
        z1 = dot2(e5pair(w, SEL23), hh[2 * j + 1], z1);
      }
      scr_z[k8 * 128 + c] = z0 + z1;
    }
    __syncthreads();
    if (tid < 32) {
      int r = tid, gc = g * 32 + r;
      float z[4] = {xe0, xe1, xe2, xe3};
      #pragma unroll
      for (int q = 0; q < 4; ++q) {
        int c = q * 32 + r;
        #pragma unroll
        for (int k8 = 0; k8 < 8; ++k8) z[q] += scr_z[k8 * 128 + c];
      }
      float c = sigmoidf_(z[1]) * c_reg + sigmoidf_(z[0]) * tanhf_(z[2]);
      c_reg = c;
      float h = sigmoidf_(z[3]) * tanhf_(c);
      h_reg = h;
      enc_out[((size_t)(b * S_ + s)) * U_ + gc] = h;
      if (s < S_ - 1) {
        float hx = __shfl_xor(h, 1);
        if (!(r & 1))
          pub64u(&hpubE[((size_t)((s + 1) & 1) * 32 + b) * 128 + g * 16 + (r >> 1)],
                 pk2(h, hx), (unsigned)(s + 1));
      }
    }
    if (s < S_ - 1 && tid < 128) {
      const u64* p = &hpubE[((size_t)((s + 1) & 1) * 32 + b) * 128 + tid];
      u64 v = ld64(p);
      while ((unsigned)(v >> 32) < (unsigned)(s + 1)) { __builtin_amdgcn_s_sleep(1); v = ld64(p); }
      h2[tid] = (unsigned)v;
    }
    __syncthreads();
  }
  if (tid < 32) {
    h_state[b * U_ + g * 32 + tid] = h_reg;
    c_state[b * U_ + g * 32 + tid] = c_reg;
  }
}

// ---------------------------------------------------------------------------
// K4: keys8 = e5m2(enc_out @ att_W2 + b2); eo8T = e5m2(enc_out)^T.
// ---------------------------------------------------------------------------
__global__ __launch_bounds__(256) void k_keys(
    const float* __restrict__ enc_out, const float* __restrict__ W2,
    const float* __restrict__ b2,
    unsigned char* __restrict__ keys8, unsigned char* __restrict__ eo8T)
{
  __shared__ float x_l[8][U_];
  int wg = blockIdx.x, tid = threadIdx.x;
  int r0 = wg * 8;
  for (int i = 0; i < 8; ++i) x_l[i][tid] = enc_out[(size_t)(r0 + i) * U_ + tid];
  __syncthreads();
  float acc[8];
  #pragma unroll
  for (int rr = 0; rr < 8; ++rr) acc[rr] = 0.f;
  for (int k = 0; k < U_; ++k) {
    float w = W2[(size_t)k * U_ + tid];
    #pragma unroll
    for (int rr = 0; rr < 8; ++rr) acc[rr] += x_l[rr][k] * w;
  }
  float bb = b2[tid];
  #pragma unroll
  for (int rr = 0; rr < 8; ++rr) {
    int r = r0 + rr;                       // r = b*128 + s
    keys8[(size_t)r * U_ + tid] = (unsigned char)f2e5(acc[rr] + bb);
    int bI = r >> 7, sI = r & 127;
    eo8T[((size_t)bI * U_ + tid) * S_ + sI] = (unsigned char)f2e5(x_l[rr][tid]);
  }
}

// ---------------------------------------------------------------------------
// K5 MEGA: WGs 0..127 = R6 decoder (4 WGs/b); WGs 128..255 = fc GEMM tiles,
// gated on per-step progress counter cnt[t] (release/relaxed + NT A-loads).
// ---------------------------------------------------------------------------
struct DecS {
  unsigned WxU[64 * 256];   // [k4][c] e5m2 ctx weights (c = 4 gates x 64)
  unsigned WhU[64 * 256];   // [k4][c] e5m2 h weights
  unsigned W1U[16 * 256];   // [k4][u] W1 rows [64g,64g+64)
  float scr_c[4 * 256];
  float scr_z[4 * 256];
  unsigned q2[160];         // half2 q, 8x20 padded
  unsigned aV2[160];
  unsigned b1p[128];
  unsigned h2[128];
  unsigned ctx2[128];
  unsigned esc2[64];
  float escw[16];
  float hsl[64];
};
struct FcS {
  uint4v Al[4][128 * 8];
  uint4v Bl[4][128 * 8];
  float rsum[4][128][2];
};
#define SMEM_MAX (sizeof(DecS) > sizeof(FcS) ? sizeof(DecS) : sizeof(FcS))

__global__ __launch_bounds__(1024) void k_dec_fc(
    const float* __restrict__ Xd, const float* __restrict__ dec_Wx,
    const float* __restrict__ Wh,
    const float* __restrict__ W1, const float* __restrict__ b1,
    const float* __restrict__ attV, const float* __restrict__ attbV,
    const unsigned char* __restrict__ keys8, const unsigned char* __restrict__ eo8T,
    const float* __restrict__ h0, const float* __restrict__ c0,
    unsigned short* __restrict__ Hbf,
    u64* __restrict__ hpub2 /*[2][32][128]*/,
    u64* __restrict__ qp2   /*[2][32][128][4]*/,
    unsigned* __restrict__ cnt /*[128]*/,
    const unsigned short* __restrict__ fcWt, const float* __restrict__ fcb,
    float* __restrict__ out, unsigned short* __restrict__ expv,
    float* __restrict__ rs_part)
{
  __shared__ __align__(16) char smem_raw[SMEM_MAX];
  int bid = blockIdx.x, tid = threadIdx.x;

  if (bid < 128) {
    // ===================== DECODER ROLE (R6 k_decoder4) =====================
    DecS& S = *(DecS*)smem_raw;
    int b = bid & 31, g = bid >> 5;        // g in 0..3
    int lane = tid & 63, wid = tid >> 6;

    for (int idx = tid; idx < 64 * 256; idx += 1024) {   // Wx (ctx rows) / Wh
      int k4 = idx >> 8, c = idx & 255;
      int gc = (c >> 6) * 256 + g * 64 + (c & 63);
      unsigned wx = 0, wh = 0;
      #pragma unroll
      for (int i = 0; i < 4; ++i) {
        int k = 4 * k4 + i;
        wx |= f2e5(dec_Wx[(size_t)k * G4 + gc]) << (8 * i);
        wh |= f2e5(Wh[(size_t)k * G4 + gc]) << (8 * i);
      }
      S.WxU[k4 * 256 + c] = wx;
      S.WhU[k4 * 256 + c] = wh;
    }
    for (int idx = tid; idx < 16 * 256; idx += 1024) {   // W1 rows [64g,64g+64)
      int k4 = idx >> 8, u = idx & 255;
      unsigned w = 0;
      #pragma unroll
      for (int i = 0; i < 4; ++i)
        w |= f2e5(W1[(size_t)(g * 64 + 4 * k4 + i) * U_ + u]) << (8 * i);
      S.W1U[k4 * 256 + u] = w;
    }
    if (tid < 128) {
      S.aV2[(tid >> 4) * 20 + (tid & 15)] = pk2(attV[2 * tid], attV[2 * tid + 1]);
      S.b1p[tid] = pk2(b1[2 * tid], b1[2 * tid + 1]);
    }
    float bV = attbV[0];
    float c_reg = 0.f, h_reg = 0.f;
    if (tid < 64) {
      h_reg = h0[b * U_ + g * 64 + tid];
      c_reg = c0[b * U_ + g * 64 + tid];
      S.hsl[tid] = h_reg;
    }
    __syncthreads();

    // initial publish: tag 1, parity 0
    if (tid < 256) {
      float qa = 0.f, qb = 0.f;
      #pragma unroll
      for (int j = 0; j < 16; ++j) {
        unsigned w = S.W1U[j * 256 + tid];
        qa = dot2(e5pair(w, SEL01), pk2(S.hsl[4 * j],     S.hsl[4 * j + 1]), qa);
        qb = dot2(e5pair(w, SEL23), pk2(S.hsl[4 * j + 2], S.hsl[4 * j + 3]), qb);
      }
      float qp = qa + qb;
      float qpx = __shfl_xor(qp, 1);
      if (!(tid & 1))
        pub64u(&qp2[(((size_t)0 * 32 + b) * 128 + (tid >> 1)) * 4 + g], pk2(qp, qpx), 1u);
    }
    if (tid < 64) {
      float hx = __shfl_xor(h_reg, 1);
      if (!(tid & 1))
        pub64u(&hpub2[((size_t)0 * 32 + b) * 128 + g * 32 + (tid >> 1)], pk2(h_reg, hx), 1u);
    }

    const unsigned NEG1 = pk2(-1.f, -1.f), POS1 = pk2(1.f, 1.f);
    const unsigned C1 = pk2(-0.333333333f, -0.333333333f);
    const unsigned C2 = pk2(0.133333333f, 0.133333333f);
    const unsigned C3 = pk2(-0.053968254f, -0.053968254f);

    const unsigned char* kb = keys8 + (size_t)b * S_ * U_;
    const unsigned char* eb = eo8T + (size_t)b * U_ * S_;

    for (int t = 0; t < T_; ++t) {
      unsigned tag = (unsigned)(t + 1);
      int par = t & 1;

      float xd0 = 0.f, xd1 = 0.f, xd2 = 0.f, xd3 = 0.f;
      if (tid < 64) {
        const float* xd = Xd + (size_t)(t * B_ + b) * G4 + g * 64 + tid;
        xd0 = xd[0]; xd1 = xd[256]; xd2 = xd[512]; xd3 = xd[768];
      }

      // P1: poll (1 h word + 4 contiguous qp words)
      if (tid < 128) {
        const u64* hp = &hpub2[((size_t)par * 32 + b) * 128 + tid];
        const u64* qp = &qp2[(((size_t)par * 32 + b) * 128 + tid) * 4];
        u64 vh, v0, v1, v2, v3;
        bool ok;
        do {
          vh = ld64(hp);
          v0 = ld64(qp); v1 = ld64(qp + 1); v2 = ld64(qp + 2); v3 = ld64(qp + 3);
          ok = ((unsigned)(vh >> 32) >= tag) & ((unsigned)(v0 >> 32) >= tag) &
               ((unsigned)(v1 >> 32) >= tag) & ((unsigned)(v2 >> 32) >= tag) &
               ((unsigned)(v3 >> 32) >= tag);
          if (!ok) __builtin_amdgcn_s_sleep(1);
        } while (!ok);
        S.h2[tid] = (unsigned)vh;
        unsigned qs = pkadd(pkadd((unsigned)v0, (unsigned)v1),
                            pkadd((unsigned)v2, (unsigned)v3));
        S.q2[(tid >> 4) * 20 + (tid & 15)] = pkadd(qs, S.b1p[tid]);
      }
      __syncthreads();

      // P2: issue key/eo loads; z_h (reg); scores
      int sI = tid >> 3, uo = tid & 7;
      int uI = tid & 255, sq = tid >> 8;
      uint4v kw0, kw1, ew0, ew1;
      {
        const uint4v* kp = (const uint4v*)(kb + (size_t)sI * U_ + uo * 32);
        kw0 = kp[0]; kw1 = kp[1];
        const uint4v* ep = (const uint4v*)(eb + (size_t)uI * S_ + sq * 32);
        ew0 = ep[0]; ew1 = ep[1];
      }
      float zreg;
      {
        int c = tid & 255, kq = tid >> 8;
        const unsigned* wp = &S.WhU[(kq * 16) * 256 + c];
        const unsigned* hh = &S.h2[kq * 32];
        float z0 = 0.f, z1 = 0.f;
        #pragma unroll
        for (int j = 0; j < 16; ++j) {
          unsigned w = wp[j * 256];
          z0 = dot2(e5pair(w, SEL01), hh[2 * j], z0);
          z1 = dot2(e5pair(w, SEL23), hh[2 * j + 1], z1);
        }
        zreg = z0 + z1;
      }
      {
        unsigned kw[8] = {kw0.x, kw0.y, kw0.z, kw0.w, kw1.x, kw1.y, kw1.z, kw1.w};
        const unsigned* qq = &S.q2[uo * 20];
        const unsigned* vv = &S.aV2[uo * 20];
        float a0 = 0.f, a1 = 0.f;
        #pragma unroll
        for (int j = 0; j < 8; ++j) {
          unsigned w = kw[j];
          unsigned x0 = pkadd(e5pair(w, SEL01), qq[2 * j]);
          unsigned x1 = pkadd(e5pair(w, SEL23), qq[2 * j + 1]);
          x0 = pkmin(pkmax(x0, NEG1), POS1);
          x1 = pkmin(pkmax(x1, NEG1), POS1);
          unsigned s0_ = pkmul(x0, x0), s1_ = pkmul(x1, x1);
          unsigned t0 = pkfma(s0_, C3, C2), t1 = pkfma(s1_, C3, C2);
          t0 = pkfma(s0_, t0, C1); t1 = pkfma(s1_, t1, C1);
          unsigned th0 = pkfma(pkmul(x0, s0_), t0, x0);
          unsigned th1 = pkfma(pkmul(x1, s1_), t1, x1);
          a0 = dot2(th0, vv[2 * j], a0);
          a1 = dot2(th1, vv[2 * j + 1], a1);
        }
        float a = a0 + a1;
        a += __shfl_xor(a, 1); a += __shfl_xor(a, 2); a += __shfl_xor(a, 4);
        float ea = __expf(a + bV);
        float ep = __shfl_xor(ea, 8);
        if (uo == 0 && !(sI & 1)) S.esc2[sI >> 1] = pk2(ea, ep);
        float dsum = ea;
        dsum += __shfl_xor(dsum, 8); dsum += __shfl_xor(dsum, 16); dsum += __shfl_xor(dsum, 32);
        if (lane == 0) S.escw[wid] = dsum;
      }
      __syncthreads();

      // P3: ctx partials over s-quarters
      {
        unsigned ewv[8] = {ew0.x, ew0.y, ew0.z, ew0.w, ew1.x, ew1.y, ew1.z, ew1.w};
        const unsigned* e2 = &S.esc2[sq * 16];
        float c0a = 0.f, c1a = 0.f;
        #pragma unroll
        for (int j = 0; j < 8; ++j) {
          unsigned w = ewv[j];
          c0a = dot2(e5pair(w, SEL01), e2[2 * j], c0a);
          c1a = dot2(e5pair(w, SEL23), e2[2 * j + 1], c1a);
        }
        S.scr_c[sq * 256 + uI] = c0a + c1a;
      }
      __syncthreads();

      // P4: ctx finalize
      if (tid < 128) {
        float d = ((S.escw[0] + S.escw[1]) + (S.escw[2] + S.escw[3])) +
                  ((S.escw[4] + S.escw[5]) + (S.escw[6] + S.escw[7])) +
                  ((S.escw[8] + S.escw[9]) + (S.escw[10] + S.escw[11])) +
                  ((S.escw[12] + S.escw[13]) + (S.escw[14] + S.escw[15]));
        float dinv = 1.0f / d;
        int u0 = 2 * tid;
        float ca = (S.scr_c[u0] + S.scr_c[256 + u0] + S.scr_c[512 + u0] + S.scr_c[768 + u0]) * dinv;
        float cb = (S.scr_c[u0 + 1] + S.scr_c[256 + u0 + 1] + S.scr_c[512 + u0 + 1] + S.scr_c[768 + u0 + 1]) * dinv;
        S.ctx2[tid] = pk2(ca, cb);
      }
      __syncthreads();

      // P5: z_ctx (+ zreg) -> scr_z
      {
        int c = tid & 255, kq = tid >> 8;
        const unsigned* wp = &S.WxU[(kq * 16) * 256 + c];
        const unsigned* cc = &S.ctx2[kq * 32];
        float z0 = 0.f, z1 = 0.f;
        #pragma unroll
        for (int j = 0; j < 16; ++j) {
          unsigned w = wp[j * 256];
          z0 = dot2(e5pair(w, SEL01), cc[2 * j], z0);
          z1 = dot2(e5pair(w, SEL23), cc[2 * j + 1], z1);
        }
        S.scr_z[kq * 256 + c] = zreg + z0 + z1;
      }
      __syncthreads();

      // P6: pointwise (64 lanes) + h publish; then progress release
      int par1 = (t + 1) & 1;
      unsigned tag2 = (unsigned)(t + 2);
      if (tid < 64) {
        int r = tid, gc = g * 64 + r;
        float z[4];
        #pragma unroll
        for (int q = 0; q < 4; ++q) {
          int c = q * 64 + r;
          z[q] = S.scr_z[c] + S.scr_z[256 + c] + S.scr_z[512 + c] + S.scr_z[768 + c];
        }
        z[0] += xd0; z[1] += xd1; z[2] += xd2; z[3] += xd3;
        float c = sigmoidf_(z[1]) * c_reg + sigmoidf_(z[0]) * tanhf_(z[2]);
        c_reg = c;
        float h = sigmoidf_(z[3]) * tanhf_(c);
        h_reg = h;
        S.hsl[r] = h;
        Hbf[(size_t)(t * B_ + b) * U_ + gc] = f2bf(h);
        if (t < T_ - 1) {
          float hx = __shfl_xor(h, 1);
          if (!(r & 1))
            pub64u(&hpub2[((size_t)par1 * 32 + b) * 128 + g * 32 + (r >> 1)], pk2(h, hx), tag2);
        }
      }
      // release: Hbf row-slice visible device-wide before cnt bump
      if (tid == 0)
        __hip_atomic_fetch_add(&cnt[t], 1u, __ATOMIC_RELEASE, __HIP_MEMORY_SCOPE_AGENT);
      __syncthreads();

      // P7: qpart publish for step t+1
      if (t < T_ - 1 && tid < 256) {
        float qa = 0.f, qb = 0.f;
        #pragma unroll
        for (int j = 0; j < 16; ++j) {
          unsigned w = S.W1U[j * 256 + tid];
          qa = dot2(e5pair(w, SEL01), pk2(S.hsl[4 * j],     S.hsl[4 * j + 1]), qa);
          qb = dot2(e5pair(w, SEL23), pk2(S.hsl[4 * j + 2], S.hsl[4 * j + 3]), qb);
        }
        float qp = qa + qb;
        float qpx = __shfl_xor(qp, 1);
        if (!(tid & 1))
          pub64u(&qp2[(((size_t)par1 * 32 + b) * 128 + (tid >> 1)) * 4 + g], pk2(qp, qpx), tag2);
      }
    }
    return;
  }

  // ======================== FC ROLE (tiles, gated) ========================
  FcS& F = *(FcS*)smem_raw;
  int w = bid - 128;
  int stid = tid & 255, sub = tid >> 8;
  int lane = tid & 63, wv = (tid >> 6) & 3;
  int wm = (wv >> 1) * 64, wn = (wv & 1) * 64;
  int gq = lane >> 4, r15 = lane & 15;

  for (int i = 0; i < 16; ++i) {
    int t4 = i * 512 + w * 4;
    if (t4 >= 8000) break;                 // uniform per WG
    int tile = t4 + sub;
    int mt = tile / 250, nt = tile % 250;
    int m0 = mt * 128, n0 = nt * 128;

    // gate: decoder steps <= 4*mtmax+3 complete for all b
    if (tid == 0) {
      int mtmax = (t4 + 3) / 250;
      while (__hip_atomic_load(&cnt[4 * mtmax + 3], __ATOMIC_RELAXED,
                               __HIP_MEMORY_SCOPE_AGENT) < 128u)
        __builtin_amdgcn_s_sleep(16);
    }
    __syncthreads();

    f32x4 acc[4][4];
    f32x4 zero = {0.f, 0.f, 0.f, 0.f};
    #pragma unroll
    for (int mi = 0; mi < 4; ++mi)
      #pragma unroll
      for (int ni = 0; ni < 4; ++ni) acc[mi][ni] = zero;

    const unsigned short* Ag = Hbf  + (size_t)m0 * 256;
    const unsigned short* Bg = fcWt + (size_t)n0 * 256;

    for (int kt = 0; kt < 4; ++kt) {
      int kk = kt * 64;
      #pragma unroll
      for (int blk = 0; blk < 4; ++blk) {
        int lin = blk * 256 + stid;
        int row = lin >> 3, kq = lin & 7;
        int slot = row * 8 + (kq ^ (row & 7));
        // A (Hbf): nontemporal (bypass caches -> coherent with release path)
        F.Al[sub][slot] = __builtin_nontemporal_load(
            (const uint4v*)(Ag + (size_t)row * 256 + kk + kq * 8));
        F.Bl[sub][slot] = *(const uint4v*)(Bg + (size_t)row * 256 + kk + kq * 8);
      }
      __syncthreads();
      #pragma unroll
      for (int kk2 = 0; kk2 < 2; ++kk2) {
        short8_t a[4], bfr[4];
        #pragma unroll
        for (int mi = 0; mi < 4; ++mi) {
          int row = wm + mi * 16 + r15;
          a[mi] = *(const short8_t*)&F.Al[sub][row * 8 + ((kk2 * 4 + gq) ^ (row & 7))];
        }
        #pragma unroll
        for (int ni = 0; ni < 4; ++ni) {
          int row = wn + ni * 16 + r15;
          bfr[ni] = *(const short8_t*)&F.Bl[sub][row * 8 + ((kk2 * 4 + gq) ^ (row & 7))];
        }
        #pragma unroll
        for (int mi = 0; mi < 4; ++mi)
          #pragma unroll
          for (int ni = 0; ni < 4; ++ni)
            acc[mi][ni] = __builtin_amdgcn_mfma_f32_16x16x32_bf16(a[mi], bfr[ni], acc[mi][ni], 0, 0, 0);
      }
      __syncthreads();
    }

    float fcb_l[4];
    #pragma unroll
    for (int ni = 0; ni < 4; ++ni) fcb_l[ni] = fcb[n0 + wn + ni * 16 + r15];

    #pragma unroll
    for (int mi = 0; mi < 4; ++mi) {
      #pragma unroll
      for (int jj = 0; jj < 4; ++jj) {
        int rloc = wm + mi * 16 + gq * 4 + jj;
        int grow = m0 + rloc;                   // = t*32 + b
        int bb = grow & 31, tt = grow >> 5;
        size_t obase = (size_t)bb * TV + (size_t)tt * V_;
        float s = 0.f;
        if (expv) {
          #pragma unroll
          for (int ni = 0; ni < 4; ++ni) {
            float v = __expf(acc[mi][ni][jj] + fcb_l[ni]);
            unsigned short us = f2bf(v);
            expv[obase + n0 + wn + ni * 16 + r15] = us;
            s += bf2f(us);
          }
        } else {
          #pragma unroll
          for (int ni = 0; ni < 4; ++ni) {
            float v = __expf(acc[mi][ni][jj] + fcb_l[ni]);
            out[obase + n0 + wn + ni * 16 + r15] = v;
            s += v;
          }
        }
        s += __shfl_xor(s, 1); s += __shfl_xor(s, 2);
        s += __shfl_xor(s, 4); s += __shfl_xor(s, 8);
        if (r15 == 0) F.rsum[sub][rloc][wv & 1] = s;
      }
    }
    __syncthreads();
    if (stid < 128)
      rs_part[(size_t)nt * 4096 + m0 + stid] =
          F.rsum[sub][stid][0] + F.rsum[sub][stid][1];
    __syncthreads();
  }
}

// ---------------------------------------------------------------------------
// K7: reduce partial row sums -> 1/sum per GEMM row
// ---------------------------------------------------------------------------
__global__ __launch_bounds__(256) void k_rowsum(
    const float* __restrict__ rs_part, float* __restrict__ row_inv)
{
  int gidx = blockIdx.x * 256 + threadIdx.x;
  float s = 0.f;
  for (int nt = 0; nt < 250; ++nt) s += rs_part[(size_t)nt * 4096 + gidx];
  row_inv[gidx] = 1.0f / s;
}

// ---------------------------------------------------------------------------
// K8a: normalize from bf16 exp -> fp32 out
// ---------------------------------------------------------------------------
__global__ __launch_bounds__(256) void k_norm_bf16(
    const unsigned short* __restrict__ expv, float* __restrict__ out,
    const float* __restrict__ row_inv)
{
  const long total = 16384000;   // 131072000 / 8
  long stride = (long)gridDim.x * 256;
  for (long i = (long)blockIdx.x * 256 + threadIdx.x; i < total; i += stride) {
    long flat = i * 8;
    int bb = (int)(flat / TV);
    int rem = (int)(flat % TV);
    int tt = rem / V_;
    float sc = row_inv[tt * 32 + bb];
    ushort8_t v = *(const ushort8_t*)&expv[flat];
    float4 o0, o1;
    o0.x = bf2f(v[0]) * sc; o0.y = bf2f(v[1]) * sc;
    o0.z = bf2f(v[2]) * sc; o0.w = bf2f(v[3]) * sc;
    o1.x = bf2f(v[4]) * sc; o1.y = bf2f(v[5]) * sc;
    o1.z = bf2f(v[6]) * sc; o1.w = bf2f(v[7]) * sc;
    *(float4*)&out[flat] = o0;
    *(float4*)&out[flat + 4] = o1;
  }
}

// ---------------------------------------------------------------------------
// K8b: fallback in-place fp32 normalize
// ---------------------------------------------------------------------------
__global__ __launch_bounds__(256) void k_norm(
    float4* __restrict__ out4, const float* __restrict__ row_inv)
{
  const long total = 32768000;
  long stride = (long)gridDim.x * 256;
  for (long i = (long)blockIdx.x * 256 + threadIdx.x; i < total; i += stride) {
    long flat = i * 4;
    int bb = (int)(flat / TV);
    int rem = (int)(flat % TV);
    int tt = rem / V_;
    float sc = row_inv[tt * 32 + bb];
    float4 v = out4[i];
    v.x *= sc; v.y *= sc; v.z *= sc; v.w *= sc;
    out4[i] = v;
  }
}

// ---------------------------------------------------------------------------
extern "C" void kernel_launch(void* const* d_in, const int* in_sizes, int n_in,
                              void* d_out, int out_size, void* d_ws, size_t ws_size,
                              hipStream_t stream) {
  (void)in_sizes; (void)n_in; (void)out_size;
  const int*   src     = (const int*)d_in[0];
  const int*   tgt     = (const int*)d_in[1];
  const float* enc_emb = (const float*)d_in[2];
  const float* enc_Wx  = (const float*)d_in[3];
  const float* enc_Wh  = (const float*)d_in[4];
  const float* enc_b   = (const float*)d_in[5];
  const float* dec_emb = (const float*)d_in[6];
  const float* dec_Wx  = (const float*)d_in[7];
  const float* dec_Wh  = (const float*)d_in[8];
  const float* dec_b   = (const float*)d_in[9];
  const float* att_W1  = (const float*)d_in[10];
  const float* att_b1  = (const float*)d_in[11];
  const float* att_W2  = (const float*)d_in[12];
  const float* att_b2  = (const float*)d_in[13];
  const float* att_V   = (const float*)d_in[14];
  const float* att_bV  = (const float*)d_in[15];
  const float* fc_W    = (const float*)d_in[16];
  const float* fc_b    = (const float*)d_in[17];
  float* out = (float*)d_out;

  char* ws = (char*)d_ws;
  size_t o = 0;
  auto alloc = [&](size_t bytes) {
    char* p = ws + o;
    o = (o + bytes + 255) & ~(size_t)255;
    return p;
  };
  float*          Xe      = (float*)alloc((size_t)S_ * B_ * G4 * 4);
  float*          Xd      = (float*)alloc((size_t)T_ * B_ * G4 * 4);
  float*          enc_out = (float*)alloc((size_t)B_ * S_ * U_ * 4);
  unsigned char*  keys8   = (unsigned char*)alloc((size_t)B_ * S_ * U_);
  unsigned char*  eo8T    = (unsigned char*)alloc((size_t)B_ * U_ * S_);
  unsigned short* Hbf     = (unsigned short*)alloc((size_t)T_ * B_ * U_ * 2);
  unsigned short* fcWt    = (unsigned short*)alloc((size_t)V_ * U_ * 2);
  float*          h_state = (float*)alloc((size_t)B_ * U_ * 4);
  float*          c_state = (float*)alloc((size_t)B_ * U_ * 4);
  float*          rs_part = (float*)alloc((size_t)250 * 4096 * 4);
  float*          row_inv = (float*)alloc((size_t)4096 * 4);
  // tagged publication buffers + progress counters (zeroed each launch)
  size_t pub_off = o;
  u64*      hpubE = (u64*)alloc((size_t)2 * 32 * 128 * 8);
  u64*      hpub2 = (u64*)alloc((size_t)2 * 32 * 128 * 8);
  u64*      qp2   = (u64*)alloc((size_t)2 * 32 * 128 * 4 * 8);
  unsigned* cnt   = (unsigned*)alloc((size_t)128 * 4);
  size_t pub_bytes = o - pub_off;
  // bf16 exp intermediate (262 MB) if workspace allows
  size_t expv_bytes = (size_t)B_ * T_ * V_ * 2;
  unsigned short* expv = nullptr;
  if (o + expv_bytes <= ws_size)
    expv = (unsigned short*)alloc(expv_bytes);

  (void)hipMemsetAsync(ws + pub_off, 0, pub_bytes, stream);
  hipLaunchKernelGGL(k_prep, dim3(3024), dim3(256), 0, stream,
                     src, tgt, enc_emb, enc_Wx, enc_b, dec_emb, dec_Wx, dec_b,
                     Xe, Xd, fc_W, fcWt);
  hipLaunchKernelGGL(k_encoder8, dim3(256), dim3(1024), 0, stream,
                     Xe, enc_Wh, enc_out, h_state, c_state, hpubE);
  hipLaunchKernelGGL(k_keys, dim3(512), dim3(256), 0, stream,
                     enc_out, att_W2, att_b2, keys8, eo8T);
  hipLaunchKernelGGL(k_dec_fc, dim3(256), dim3(1024), 0, stream,
                     Xd, dec_Wx, dec_Wh, att_W1, att_b1, att_V, att_bV,
                     keys8, eo8T, h_state, c_state, Hbf, hpub2, qp2, cnt,
                     fcWt, fc_b, out, expv, rs_part);
  hipLaunchKernelGGL(k_rowsum, dim3(16), dim3(256), 0, stream, rs_part, row_inv);
  if (expv)
    hipLaunchKernelGGL(k_norm_bf16, dim3(4096), dim3(256), 0, stream,
                       expv, out, row_inv);
  else
    hipLaunchKernelGGL(k_norm, dim3(2048), dim3(256), 0, stream,
                       (float4*)d_out, row_inv);
}

// Round 14
// 1521.485 us; speedup vs baseline: 1.1590x; 1.1590x over previous
//
#include <hip/hip_runtime.h>
#include <hip/hip_bf16.h>
#include <hip/hip_fp16.h>
#include <cstdint>
#include <cstddef>

#define B_ 32
#define S_ 128
#define T_ 128
#define E_ 128
#define U_ 256
#define V_ 32000
#define G4 1024          // 4*U
#define TV 4096000       // T_*V_

typedef __attribute__((ext_vector_type(8))) short short8_t;   // 8 bf16
typedef __attribute__((ext_vector_type(8))) unsigned short ushort8_t;
typedef __attribute__((ext_vector_type(4))) float f32x4;
typedef __attribute__((ext_vector_type(4))) unsigned uint4v;
typedef unsigned long long u64;

static __device__ __forceinline__ unsigned short f2bf(float x) {
  union { float f; unsigned int u; } v; v.f = x;
  unsigned int r = (v.u + 0x7fffu + ((v.u >> 16) & 1u)) >> 16;
  return (unsigned short)r;
}
static __device__ __forceinline__ float bf2f(unsigned short u) {
  return __uint_as_float(((unsigned)u) << 16);
}
static __device__ __forceinline__ float sigmoidf_(float x) {
  return 1.0f / (1.0f + __expf(-x));
}
static __device__ __forceinline__ float tanhf_(float x) {
  float e = __expf(2.0f * x);
  return 1.0f - 2.0f / (e + 1.0f);
}

// ---- e5m2 (truncated fp16) encode ----
static __device__ __forceinline__ unsigned int f2e5(float x) {
  __half h = __float2half(x);
  __half_raw hr = *(__half_raw*)&h;
  unsigned int u = hr.x;
  unsigned int r = (u + 0x7Fu + ((u >> 8) & 1u)) >> 8;   // RNE to 8 bits
  return r & 0xFFu;
}

// ---- packed fp16 helpers ----
static __device__ __forceinline__ unsigned pk2(float a, float b) {
  auto h = __builtin_amdgcn_cvt_pkrtz(a, b);
  return __builtin_bit_cast(unsigned, h);
}
#define SEL01 0x05000400u   // bytes -> half2(b0<<8, b1<<8)
#define SEL23 0x07000600u
static __device__ __forceinline__ unsigned e5pair(unsigned w, unsigned sel) {
  return __builtin_amdgcn_perm(w, 0u, sel);
}
static __device__ __forceinline__ float dot2(unsigned a, unsigned b, float c) {
  float d;
  asm("v_dot2_f32_f16 %0, %1, %2, %3" : "=v"(d) : "v"(a), "v"(b), "v"(c));
  return d;
}
static __device__ __forceinline__ unsigned pkadd(unsigned a, unsigned b) {
  unsigned d; asm("v_pk_add_f16 %0, %1, %2" : "=v"(d) : "v"(a), "v"(b)); return d;
}
static __device__ __forceinline__ unsigned pkmul(unsigned a, unsigned b) {
  unsigned d; asm("v_pk_mul_f16 %0, %1, %2" : "=v"(d) : "v"(a), "v"(b)); return d;
}
static __device__ __forceinline__ unsigned pkfma(unsigned a, unsigned b, unsigned c) {
  unsigned d; asm("v_pk_fma_f16 %0, %1, %2, %3" : "=v"(d) : "v"(a), "v"(b), "v"(c)); return d;
}
static __device__ __forceinline__ unsigned pkmax(unsigned a, unsigned b) {
  unsigned d; asm("v_pk_max_f16 %0, %1, %2" : "=v"(d) : "v"(a), "v"(b)); return d;
}
static __device__ __forceinline__ unsigned pkmin(unsigned a, unsigned b) {
  unsigned d; asm("v_pk_min_f16 %0, %1, %2" : "=v"(d) : "v"(a), "v"(b)); return d;
}

// ---- tagged agent-scope publication ----
static __device__ __forceinline__ void pub64u(u64* p, unsigned val, unsigned tag) {
  u64 v = ((u64)tag << 32) | (u64)val;
  __hip_atomic_store(p, v, __ATOMIC_RELAXED, __HIP_MEMORY_SCOPE_AGENT);
}
static __device__ __forceinline__ u64 ld64(const u64* p) {
  return __hip_atomic_load(p, __ATOMIC_RELAXED, __HIP_MEMORY_SCOPE_AGENT);
}

// ---------------------------------------------------------------------------
// K1: embedding gather + x@Wx + bias precompute for encoder and decoder.
// ---------------------------------------------------------------------------
__global__ __launch_bounds__(256) void k_prep_x(
    const int* __restrict__ src, const int* __restrict__ tgt,
    const float* __restrict__ enc_emb, const float* __restrict__ enc_Wx,
    const float* __restrict__ enc_b,
    const float* __restrict__ dec_emb, const float* __restrict__ dec_Wx,
    const float* __restrict__ dec_b,
    float* __restrict__ Xe, float* __restrict__ Xd)
{
  __shared__ float emb_l[8][E_];
  int wg = blockIdx.x;
  int tid = threadIdx.x;
  bool is_dec = (wg >= 512);
  int r0 = (is_dec ? (wg - 512) : wg) * 8;
  const float* emb  = is_dec ? dec_emb : enc_emb;
  const float* W    = is_dec ? (dec_Wx + (size_t)U_ * G4) : enc_Wx;
  const float* bias = is_dec ? dec_b : enc_b;
  float* Xout = is_dec ? Xd : Xe;

  for (int i = 0; i < 4; ++i) {
    int lin = i * 256 + tid;
    int rr = lin >> 7, k = lin & 127;
    int r = r0 + rr;               // r = step*32 + b
    int b = r & 31, st = r >> 5;
    int tok;
    if (is_dec) tok = tgt[b * T_ + (st > 0 ? st - 1 : 0)];
    else        tok = src[b * S_ + st];
    emb_l[rr][k] = emb[(size_t)tok * E_ + k];
  }
  __syncthreads();

  float acc[8][4];
  #pragma unroll
  for (int rr = 0; rr < 8; ++rr)
    #pragma unroll
    for (int cc = 0; cc < 4; ++cc) acc[rr][cc] = 0.f;

  for (int k = 0; k < E_; ++k) {
    float w0 = W[(size_t)k * G4 + tid];
    float w1 = W[(size_t)k * G4 + tid + 256];
    float w2 = W[(size_t)k * G4 + tid + 512];
    float w3 = W[(size_t)k * G4 + tid + 768];
    #pragma unroll
    for (int rr = 0; rr < 8; ++rr) {
      float e = emb_l[rr][k];
      acc[rr][0] += e * w0; acc[rr][1] += e * w1;
      acc[rr][2] += e * w2; acc[rr][3] += e * w3;
    }
  }
  #pragma unroll
  for (int rr = 0; rr < 8; ++rr) {
    int r = r0 + rr;
    #pragma unroll
    for (int cc = 0; cc < 4; ++cc) {
      int col = tid + cc * 256;
      Xout[(size_t)r * G4 + col] = acc[rr][cc] + bias[col];
    }
  }
}

// ---------------------------------------------------------------------------
// K2: transpose fc_W [256][32000] f32 -> fcWt [32000][256] bf16
// ---------------------------------------------------------------------------
__global__ __launch_bounds__(256) void k_prep_fcw(
    const float* __restrict__ fcW, unsigned short* __restrict__ fcWt)
{
  __shared__ float tile[64][65];
  int bid = blockIdx.x, tid = threadIdx.x;
  int n0 = (bid % 500) * 64, k0 = (bid / 500) * 64;
  for (int i = 0; i < 16; ++i) {
    int lin = i * 256 + tid;
    int k = lin >> 6, n = lin & 63;
    tile[k][n] = fcW[(size_t)(k0 + k) * V_ + n0 + n];
  }
  __syncthreads();
  for (int i = 0; i < 16; ++i) {
    int lin = i * 256 + tid;
    int n = lin >> 6, k = lin & 63;
    fcWt[(size_t)(n0 + n) * 256 + k0 + k] = f2bf(tile[k][n]);
  }
}

// ---------------------------------------------------------------------------
// K3: encoder LSTM, 8 WGs x 1024 threads per b (R10 verbatim).
// ---------------------------------------------------------------------------
__global__ __launch_bounds__(1024) void k_encoder8(
    const float* __restrict__ Xe, const float* __restrict__ Wh,
    float* __restrict__ enc_out, float* __restrict__ h_state,
    float* __restrict__ c_state, u64* __restrict__ hpubE /*[2][32][128]*/)
{
  __shared__ unsigned int WhU[64 * 128];   // [k4][c], 32KB
  __shared__ unsigned int h2[128];
  __shared__ float scr_z[8 * 128];

  int bid = blockIdx.x, tid = threadIdx.x;
  int b = bid & 31, g = bid >> 5;          // 8 WGs of b share an XCD

  for (int idx = tid; idx < 64 * 128; idx += 1024) {
    int k4 = idx >> 7, c = idx & 127;
    int gc = (c >> 5) * 256 + g * 32 + (c & 31);
    unsigned w = 0;
    #pragma unroll
    for (int i = 0; i < 4; ++i)
      w |= f2e5(Wh[(size_t)(4 * k4 + i) * G4 + gc]) << (8 * i);
    WhU[k4 * 128 + c] = w;
  }
  if (tid < 128) h2[tid] = 0u;
  float c_reg = 0.f, h_reg = 0.f;
  __syncthreads();

  for (int s = 0; s < S_; ++s) {
    float xe0 = 0.f, xe1 = 0.f, xe2 = 0.f, xe3 = 0.f;
    if (tid < 32) {
      const float* xe = Xe + (size_t)(s * B_ + b) * G4 + g * 32 + tid;
      xe0 = xe[0]; xe1 = xe[256]; xe2 = xe[512]; xe3 = xe[768];
    }
    // z phase (c = tid&127, k8 = tid>>7)
    {
      int c = tid & 127, k8 = tid >> 7;
      const unsigned* wp = &WhU[(k8 * 8) * 128 + c];
      const unsigned* hh = &h2[k8 * 16];
      float z0 = 0.f, z1 = 0.f;
      #pragma unroll
      for (int j = 0; j < 8; ++j) {
        unsigned w = wp[j * 128];
        z0 = dot2(e5pair(w, SEL01), hh[2 * j], z0);
        z1 = dot2(e5pair(w, SEL23), hh[2 * j + 1], z1);
      }
      scr_z[k8 * 128 + c] = z0 + z1;
    }
    __syncthreads();
    // pointwise + publish + poll-next
    if (tid < 32) {
      int r = tid, gc = g * 32 + r;
      float z[4] = {xe0, xe1, xe2, xe3};
      #pragma unroll
      for (int q = 0; q < 4; ++q) {
        int c = q * 32 + r;
        #pragma unroll
        for (int k8 = 0; k8 < 8; ++k8) z[q] += scr_z[k8 * 128 + c];
      }
      float c = sigmoidf_(z[1]) * c_reg + sigmoidf_(z[0]) * tanhf_(z[2]);
      c_reg = c;
      float h = sigmoidf_(z[3]) * tanhf_(c);
      h_reg = h;
      enc_out[((size_t)(b * S_ + s)) * U_ + gc] = h;
      if (s < S_ - 1) {
        float hx = __shfl_xor(h, 1);
        if (!(r & 1))
          pub64u(&hpubE[((size_t)((s + 1) & 1) * 32 + b) * 128 + g * 16 + (r >> 1)],
                 pk2(h, hx), (unsigned)(s + 1));
      }
    }
    if (s < S_ - 1 && tid < 128) {
      const u64* p = &hpubE[((size_t)((s + 1) & 1) * 32 + b) * 128 + tid];
      u64 v = ld64(p);
      while ((unsigned)(v >> 32) < (unsigned)(s + 1)) { __builtin_amdgcn_s_sleep(1); v = ld64(p); }
      h2[tid] = (unsigned)v;
    }
    __syncthreads();
  }
  if (tid < 32) {
    h_state[b * U_ + g * 32 + tid] = h_reg;
    c_state[b * U_ + g * 32 + tid] = c_reg;
  }
}

// ---------------------------------------------------------------------------
// K4: keys8 = e5m2(enc_out @ att_W2 + b2); eo8T = e5m2(enc_out)^T.
// ---------------------------------------------------------------------------
__global__ __launch_bounds__(256) void k_keys(
    const float* __restrict__ enc_out, const float* __restrict__ W2,
    const float* __restrict__ b2,
    unsigned char* __restrict__ keys8, unsigned char* __restrict__ eo8T)
{
  __shared__ float x_l[8][U_];
  int wg = blockIdx.x, tid = threadIdx.x;
  int r0 = wg * 8;
  for (int i = 0; i < 8; ++i) x_l[i][tid] = enc_out[(size_t)(r0 + i) * U_ + tid];
  __syncthreads();
  float acc[8];
  #pragma unroll
  for (int rr = 0; rr < 8; ++rr) acc[rr] = 0.f;
  for (int k = 0; k < U_; ++k) {
    float w = W2[(size_t)k * U_ + tid];
    #pragma unroll
    for (int rr = 0; rr < 8; ++rr) acc[rr] += x_l[rr][k] * w;
  }
  float bb = b2[tid];
  #pragma unroll
  for (int rr = 0; rr < 8; ++rr) {
    int r = r0 + rr;                       // r = b*128 + s
    keys8[(size_t)r * U_ + tid] = (unsigned char)f2e5(acc[rr] + bb);
    int bI = r >> 7, sI = r & 127;
    eo8T[((size_t)bI * U_ + tid) * S_ + sI] = (unsigned char)f2e5(x_l[rr][tid]);
  }
}

// ---------------------------------------------------------------------------
// K5: decoder (R10 verbatim — proven 765us structure).
// ---------------------------------------------------------------------------
__global__ __launch_bounds__(1024) void k_decoder(
    const float* __restrict__ Xd, const float* __restrict__ dec_Wx,
    const float* __restrict__ Wh,
    const float* __restrict__ W1, const float* __restrict__ b1,
    const float* __restrict__ attV, const float* __restrict__ attbV,
    const unsigned char* __restrict__ keys8, const unsigned char* __restrict__ eo8T,
    const float* __restrict__ h0, const float* __restrict__ c0,
    unsigned short* __restrict__ Hbf,
    u64* __restrict__ hpub2 /*[2][32][128]*/)
{
  __shared__ unsigned int WxU[64 * 128];   // [k4][c] e5m2 ctx weights, 32KB
  __shared__ unsigned int WhU[64 * 128];   // [k4][c] e5m2 h weights, 32KB
  __shared__ unsigned int W1U[64 * 256];   // [k4][u] full W1, 64KB
  __shared__ float scr_q[4 * 256];         // q k-quarter partials
  __shared__ float scr_c[4 * 256];         // ctx s-quarter partials (unnormalized)
  __shared__ float scr_z[8 * 128];         // z partials
  __shared__ unsigned int q2[160];         // half2 q, oct-padded 8x20
  __shared__ unsigned int aV2[160];
  __shared__ unsigned int h2[128];
  __shared__ unsigned int ctx2[128];       // unnormalized ctx pairs
  __shared__ unsigned int esc2[64];
  __shared__ float escw[16];
  __shared__ float b1_l[256];

  int bid = blockIdx.x, tid = threadIdx.x;
  int b = bid & 31, g = bid >> 5;          // 8 WGs of b on one XCD
  int lane = tid & 63, wid = tid >> 6;

  // ---- one-time staging ----
  for (int idx = tid; idx < 64 * 128; idx += 1024) {   // Wx(ctx rows)/Wh slices
    int k4 = idx >> 7, c = idx & 127;
    int gc = (c >> 5) * 256 + g * 32 + (c & 31);
    unsigned wx = 0, wh = 0;
    #pragma unroll
    for (int i = 0; i < 4; ++i) {
      int k = 4 * k4 + i;
      wx |= f2e5(dec_Wx[(size_t)k * G4 + gc]) << (8 * i);
      wh |= f2e5(Wh[(size_t)k * G4 + gc]) << (8 * i);
    }
    WxU[k4 * 128 + c] = wx;
    WhU[k4 * 128 + c] = wh;
  }
  for (int idx = tid; idx < 64 * 256; idx += 1024) {   // full W1
    int k4 = idx >> 8, u = idx & 255;
    unsigned w = 0;
    #pragma unroll
    for (int i = 0; i < 4; ++i)
      w |= f2e5(W1[(size_t)(4 * k4 + i) * U_ + u]) << (8 * i);
    W1U[k4 * 256 + u] = w;
  }
  if (tid < 128) {
    int p = tid;                           // pair index
    aV2[(p >> 4) * 20 + (p & 15)] = pk2(attV[2 * p], attV[2 * p + 1]);
  }
  if (tid < 256) b1_l[tid] = b1[tid];
  float bV = attbV[0];
  float c_reg = 0.f, h_reg = 0.f;
  if (tid < 32) {
    h_reg = h0[b * U_ + g * 32 + tid];
    c_reg = c0[b * U_ + g * 32 + tid];
  }
  __syncthreads();

  // ---- initial publish + initial poll (tag 1, parity 0) ----
  if (tid < 32) {
    float hx = __shfl_xor(h_reg, 1);
    if (!(tid & 1))
      pub64u(&hpub2[((size_t)0 * 32 + b) * 128 + g * 16 + (tid >> 1)], pk2(h_reg, hx), 1u);
  }
  if (tid < 128) {
    const u64* hp = &hpub2[((size_t)0 * 32 + b) * 128 + tid];
    u64 vh = ld64(hp);
    while ((unsigned)(vh >> 32) < 1u) { __builtin_amdgcn_s_sleep(1); vh = ld64(hp); }
    h2[tid] = (unsigned)vh;
  }
  __syncthreads();

  const unsigned NEG1 = pk2(-1.f, -1.f), POS1 = pk2(1.f, 1.f);
  const unsigned C1 = pk2(-0.333333333f, -0.333333333f);
  const unsigned C2 = pk2(0.133333333f, 0.133333333f);
  const unsigned C3 = pk2(-0.053968254f, -0.053968254f);

  const unsigned char* kb = keys8 + (size_t)b * S_ * U_;
  const unsigned char* eb = eo8T + (size_t)b * U_ * S_;

  for (int t = 0; t < T_; ++t) {
    // ---- Xd prefetch ----
    float xd0 = 0.f, xd1 = 0.f, xd2 = 0.f, xd3 = 0.f;
    if (tid < 32) {
      const float* xd = Xd + (size_t)(t * B_ + b) * G4 + g * 32 + tid;
      xd0 = xd[0]; xd1 = xd[256]; xd2 = xd[512]; xd3 = xd[768];
    }

    // ---- P2: issue key/eo loads; q k-quarters over all 1024 threads ----
    int sI = tid >> 3, uo = tid & 7;          // scores mapping (P3)
    int uI = tid & 255, sq = tid >> 8;        // ctx mapping (P4)
    uint4v kA, kB, eA, eB;
    {
      const uint4v* kp = (const uint4v*)(kb + (size_t)sI * U_ + uo * 32);
      kA = kp[0]; kB = kp[1];
      const uint4v* ep = (const uint4v*)(eb + (size_t)uI * S_ + sq * 32);
      eA = ep[0]; eB = ep[1];
    }
    {
      int c = tid & 255, kq = tid >> 8;
      const unsigned* wp = &W1U[(kq * 16) * 256 + c];
      const unsigned* hh = &h2[kq * 32];
      float qa = 0.f, qb = 0.f;
      #pragma unroll
      for (int j = 0; j < 16; ++j) {
        unsigned w = wp[j * 256];
        qa = dot2(e5pair(w, SEL01), hh[2 * j], qa);
        qb = dot2(e5pair(w, SEL23), hh[2 * j + 1], qb);
      }
      scr_q[kq * 256 + c] = qa + qb;
    }
    __syncthreads();

    // ---- P2b: merge q quarters -> half2 pairs ----
    if (tid < 128) {
      int u0 = 2 * tid;
      float q0 = scr_q[u0] + scr_q[256 + u0] + scr_q[512 + u0] + scr_q[768 + u0] + b1_l[u0];
      float q1 = scr_q[u0 + 1] + scr_q[256 + u0 + 1] + scr_q[512 + u0 + 1] + scr_q[768 + u0 + 1] + b1_l[u0 + 1];
      q2[(tid >> 4) * 20 + (tid & 15)] = pk2(q0, q1);
    }
    __syncthreads();

    // ---- P3: scores (s = tid>>3, u-oct = tid&7, 32 u each) ----
    {
      unsigned kw[8] = {kA.x, kA.y, kA.z, kA.w, kB.x, kB.y, kB.z, kB.w};
      const unsigned* qq = &q2[uo * 20];
      const unsigned* vv = &aV2[uo * 20];
      float a0 = 0.f, a1 = 0.f;
      #pragma unroll
      for (int j = 0; j < 8; ++j) {
        unsigned w = kw[j];
        unsigned x0 = pkadd(e5pair(w, SEL01), qq[2 * j]);
        unsigned x1 = pkadd(e5pair(w, SEL23), qq[2 * j + 1]);
        x0 = pkmin(pkmax(x0, NEG1), POS1);
        x1 = pkmin(pkmax(x1, NEG1), POS1);
        unsigned s0_ = pkmul(x0, x0), s1_ = pkmul(x1, x1);
        unsigned t0 = pkfma(s0_, C3, C2), t1 = pkfma(s1_, C3, C2);
        t0 = pkfma(s0_, t0, C1); t1 = pkfma(s1_, t1, C1);
        unsigned th0 = pkfma(pkmul(x0, s0_), t0, x0);
        unsigned th1 = pkfma(pkmul(x1, s1_), t1, x1);
        a0 = dot2(th0, vv[2 * j], a0);
        a1 = dot2(th1, vv[2 * j + 1], a1);
      }
      float a = a0 + a1;
      a += __shfl_xor(a, 1); a += __shfl_xor(a, 2); a += __shfl_xor(a, 4);
      float ea = __expf(a + bV);
      float ep = __shfl_xor(ea, 8);            // s^1's value
      if (uo == 0 && !(sI & 1)) esc2[sI >> 1] = pk2(ea, ep);
      float dsum = ea;                         // sum 8 distinct s in wave
      dsum += __shfl_xor(dsum, 8); dsum += __shfl_xor(dsum, 16); dsum += __shfl_xor(dsum, 32);
      if (lane == 0) escw[wid] = dsum;
    }
    __syncthreads();

    // ---- P4: ctx partials (u = tid&255, s-quarter = tid>>8, 32 s each) ----
    {
      unsigned ewv[8] = {eA.x, eA.y, eA.z, eA.w, eB.x, eB.y, eB.z, eB.w};
      const unsigned* e2 = &esc2[sq * 16];
      float c0a = 0.f, c1a = 0.f;
      #pragma unroll
      for (int j = 0; j < 8; ++j) {
        unsigned w = ewv[j];
        c0a = dot2(e5pair(w, SEL01), e2[2 * j], c0a);
        c1a = dot2(e5pair(w, SEL23), e2[2 * j + 1], c1a);
      }
      scr_c[sq * 256 + uI] = c0a + c1a;
    }
    __syncthreads();

    // ---- P4b: unnormalized ctx pairs ----
    if (tid < 128) {
      int u0 = 2 * tid;
      float ca = scr_c[u0] + scr_c[256 + u0] + scr_c[512 + u0] + scr_c[768 + u0];
      float cb = scr_c[u0 + 1] + scr_c[256 + u0 + 1] + scr_c[512 + u0 + 1] + scr_c[768 + u0 + 1];
      ctx2[tid] = pk2(ca, cb);
    }
    __syncthreads();

    // ---- P5: z = z_h + z_ctx * dinv (c = tid&127, k-8th = tid>>7) ----
    {
      float d = ((escw[0] + escw[1]) + (escw[2] + escw[3])) +
                ((escw[4] + escw[5]) + (escw[6] + escw[7])) +
                ((escw[8] + escw[9]) + (escw[10] + escw[11])) +
                ((escw[12] + escw[13]) + (escw[14] + escw[15]));
      float dinv = 1.0f / d;
      int c = tid & 127, k8 = tid >> 7;
      const unsigned* wxp = &WxU[(k8 * 8) * 128 + c];
      const unsigned* whp = &WhU[(k8 * 8) * 128 + c];
      const unsigned* cc = &ctx2[k8 * 16];
      const unsigned* hh = &h2[k8 * 16];
      float zx0 = 0.f, zx1 = 0.f, zh0 = 0.f, zh1 = 0.f;
      #pragma unroll
      for (int j = 0; j < 8; ++j) {
        unsigned wx = wxp[j * 128], wh = whp[j * 128];
        zx0 = dot2(e5pair(wx, SEL01), cc[2 * j], zx0);
        zx1 = dot2(e5pair(wx, SEL23), cc[2 * j + 1], zx1);
        zh0 = dot2(e5pair(wh, SEL01), hh[2 * j], zh0);
        zh1 = dot2(e5pair(wh, SEL23), hh[2 * j + 1], zh1);
      }
      scr_z[k8 * 128 + c] = (zh0 + zh1) + (zx0 + zx1) * dinv;
    }
    __syncthreads();

    // ---- P6: pointwise (32 lanes) + h publish + poll-next ----
    if (tid < 32) {
      int r = tid, gc = g * 32 + r;
      float z[4] = {xd0, xd1, xd2, xd3};
      #pragma unroll
      for (int q = 0; q < 4; ++q) {
        int c = q * 32 + r;
        #pragma unroll
        for (int k8 = 0; k8 < 8; ++k8) z[q] += scr_z[k8 * 128 + c];
      }
      float c = sigmoidf_(z[1]) * c_reg + sigmoidf_(z[0]) * tanhf_(z[2]);
      c_reg = c;
      float h = sigmoidf_(z[3]) * tanhf_(c);
      h_reg = h;
      Hbf[(size_t)(t * B_ + b) * U_ + gc] = f2bf(h);
      if (t < T_ - 1) {
        int par1 = (t + 1) & 1;
        float hx = __shfl_xor(h, 1);
        if (!(r & 1))
          pub64u(&hpub2[((size_t)par1 * 32 + b) * 128 + g * 16 + (r >> 1)],
                 pk2(h, hx), (unsigned)(t + 2));
      }
    }
    if (t < T_ - 1 && tid < 128) {
      int par1 = (t + 1) & 1;
      unsigned tag2 = (unsigned)(t + 2);
      const u64* hp = &hpub2[((size_t)par1 * 32 + b) * 128 + tid];
      u64 vh = ld64(hp);
      while ((unsigned)(vh >> 32) < tag2) { __builtin_amdgcn_s_sleep(1); vh = ld64(hp); }
      h2[tid] = (unsigned)vh;
    }
    __syncthreads();
  }
}

// ---------------------------------------------------------------------------
// K6 v2: fc GEMM, 2 mt-tiles per WG sharing one B-tile (B LDS-resident).
// grid 4000: nt = bid>>4 (0..249), pair = bid&15 -> mt = 2*pair, 2*pair+1.
// ---------------------------------------------------------------------------
__global__ __launch_bounds__(256) void k_fc(
    const unsigned short* __restrict__ Hbf, const unsigned short* __restrict__ fcWt,
    const float* __restrict__ fcb, float* __restrict__ out,
    unsigned short* __restrict__ expv,
    float* __restrict__ rs_part)
{
  __shared__ uint4v Bl[128 * 32];   // [row][32 slots], full K=256, 64KB
  __shared__ uint4v Al[128 * 8];    // per-kt A tile, 16KB
  __shared__ float rsum_l[128][2];

  int bid = blockIdx.x, tid = threadIdx.x;
  int nt = bid >> 4, pr = bid & 15;
  int n0 = nt * 128;
  int lane = tid & 63, wave = tid >> 6;
  int wm = (wave >> 1) * 64, wn = (wave & 1) * 64;
  int g = lane >> 4, r15 = lane & 15;

  // ---- stage full B tile once (row-major K, XOR-swizzled per 8-slot group) ----
  const unsigned short* Bg = fcWt + (size_t)n0 * 256;
  for (int idx = tid; idx < 128 * 32; idx += 256) {
    int row = idx >> 5, slot = idx & 31;
    int kt = slot >> 3, kq = slot & 7;
    Bl[row * 32 + kt * 8 + (kq ^ (row & 7))] =
        *(const uint4v*)(Bg + (size_t)row * 256 + kt * 64 + kq * 8);
  }

  float fcb_l[4];
  #pragma unroll
  for (int ni = 0; ni < 4; ++ni) fcb_l[ni] = fcb[n0 + wn + ni * 16 + r15];

  for (int half = 0; half < 2; ++half) {
    int mt = pr * 2 + half;
    int m0 = mt * 128;
    const unsigned short* Ag = Hbf + (size_t)m0 * 256;

    f32x4 acc[4][4];
    f32x4 zero = {0.f, 0.f, 0.f, 0.f};
    #pragma unroll
    for (int mi = 0; mi < 4; ++mi)
      #pragma unroll
      for (int ni = 0; ni < 4; ++ni) acc[mi][ni] = zero;

    for (int kt = 0; kt < 4; ++kt) {
      int kk = kt * 64;
      #pragma unroll
      for (int blk = 0; blk < 4; ++blk) {
        int lin = blk * 256 + tid;
        int row = lin >> 3, kq = lin & 7;
        Al[row * 8 + (kq ^ (row & 7))] =
            *(const uint4v*)(Ag + (size_t)row * 256 + kk + kq * 8);
      }
      __syncthreads();
      #pragma unroll
      for (int kk2 = 0; kk2 < 2; ++kk2) {
        short8_t a[4], bfr[4];
        #pragma unroll
        for (int mi = 0; mi < 4; ++mi) {
          int row = wm + mi * 16 + r15;
          a[mi] = *(const short8_t*)&Al[row * 8 + ((kk2 * 4 + g) ^ (row & 7))];
        }
        #pragma unroll
        for (int ni = 0; ni < 4; ++ni) {
          int row = wn + ni * 16 + r15;
          bfr[ni] = *(const short8_t*)&Bl[row * 32 + kt * 8 + ((kk2 * 4 + g) ^ (row & 7))];
        }
        #pragma unroll
        for (int mi = 0; mi < 4; ++mi)
          #pragma unroll
          for (int ni = 0; ni < 4; ++ni)
            acc[mi][ni] = __builtin_amdgcn_mfma_f32_16x16x32_bf16(a[mi], bfr[ni], acc[mi][ni], 0, 0, 0);
      }
      __syncthreads();
    }

    #pragma unroll
    for (int mi = 0; mi < 4; ++mi) {
      #pragma unroll
      for (int jj = 0; jj < 4; ++jj) {
        int rloc = wm + mi * 16 + g * 4 + jj;
        int grow = m0 + rloc;                   // = t*32 + b
        int bb = grow & 31, tt = grow >> 5;
        size_t obase = (size_t)bb * TV + (size_t)tt * V_;
        float s = 0.f;
        if (expv) {
          #pragma unroll
          for (int ni = 0; ni < 4; ++ni) {
            float v = __expf(acc[mi][ni][jj] + fcb_l[ni]);
            unsigned short us = f2bf(v);
            expv[obase + n0 + wn + ni * 16 + r15] = us;
            s += bf2f(us);
          }
        } else {
          #pragma unroll
          for (int ni = 0; ni < 4; ++ni) {
            float v = __expf(acc[mi][ni][jj] + fcb_l[ni]);
            out[obase + n0 + wn + ni * 16 + r15] = v;
            s += v;
          }
        }
        s += __shfl_xor(s, 1); s += __shfl_xor(s, 2);
        s += __shfl_xor(s, 4); s += __shfl_xor(s, 8);
        if (r15 == 0) rsum_l[rloc][wave & 1] = s;
      }
    }
    __syncthreads();
    if (tid < 128)
      rs_part[(size_t)nt * 4096 + m0 + tid] = rsum_l[tid][0] + rsum_l[tid][1];
    __syncthreads();
  }
}

// ---------------------------------------------------------------------------
// K7: reduce partial row sums -> 1/sum per GEMM row
// ---------------------------------------------------------------------------
__global__ __launch_bounds__(256) void k_rowsum(
    const float* __restrict__ rs_part, float* __restrict__ row_inv)
{
  int gidx = blockIdx.x * 256 + threadIdx.x;
  float s = 0.f;
  for (int nt = 0; nt < 250; ++nt) s += rs_part[(size_t)nt * 4096 + gidx];
  row_inv[gidx] = 1.0f / s;
}

// ---------------------------------------------------------------------------
// K8a: normalize from bf16 exp -> fp32 out
// ---------------------------------------------------------------------------
__global__ __launch_bounds__(256) void k_norm_bf16(
    const unsigned short* __restrict__ expv, float* __restrict__ out,
    const float* __restrict__ row_inv)
{
  const long total = 16384000;   // 131072000 / 8
  long stride = (long)gridDim.x * 256;
  for (long i = (long)blockIdx.x * 256 + threadIdx.x; i < total; i += stride) {
    long flat = i * 8;
    int bb = (int)(flat / TV);
    int rem = (int)(flat % TV);
    int tt = rem / V_;
    float sc = row_inv[tt * 32 + bb];
    ushort8_t v = *(const ushort8_t*)&expv[flat];
    float4 o0, o1;
    o0.x = bf2f(v[0]) * sc; o0.y = bf2f(v[1]) * sc;
    o0.z = bf2f(v[2]) * sc; o0.w = bf2f(v[3]) * sc;
    o1.x = bf2f(v[4]) * sc; o1.y = bf2f(v[5]) * sc;
    o1.z = bf2f(v[6]) * sc; o1.w = bf2f(v[7]) * sc;
    *(float4*)&out[flat] = o0;
    *(float4*)&out[flat + 4] = o1;
  }
}

// ---------------------------------------------------------------------------
// K8b: fallback in-place fp32 normalize
// ---------------------------------------------------------------------------
__global__ __launch_bounds__(256) void k_norm(
    float4* __restrict__ out4, const float* __restrict__ row_inv)
{
  const long total = 32768000;
  long stride = (long)gridDim.x * 256;
  for (long i = (long)blockIdx.x * 256 + threadIdx.x; i < total; i += stride) {
    long flat = i * 4;
    int bb = (int)(flat / TV);
    int rem = (int)(flat % TV);
    int tt = rem / V_;
    float sc = row_inv[tt * 32 + bb];
    float4 v = out4[i];
    v.x *= sc; v.y *= sc; v.z *= sc; v.w *= sc;
    out4[i] = v;
  }
}

// ---------------------------------------------------------------------------
extern "C" void kernel_launch(void* const* d_in, const int* in_sizes, int n_in,
                              void* d_out, int out_size, void* d_ws, size_t ws_size,
                              hipStream_t stream) {
  (void)in_sizes; (void)n_in; (void)out_size;
  const int*   src     = (const int*)d_in[0];
  const int*   tgt     = (const int*)d_in[1];
  const float* enc_emb = (const float*)d_in[2];
  const float* enc_Wx  = (const float*)d_in[3];
  const float* enc_Wh  = (const float*)d_in[4];
  const float* enc_b   = (const float*)d_in[5];
  const float* dec_emb = (const float*)d_in[6];
  const float* dec_Wx  = (const float*)d_in[7];
  const float* dec_Wh  = (const float*)d_in[8];
  const float* dec_b   = (const float*)d_in[9];
  const float* att_W1  = (const float*)d_in[10];
  const float* att_b1  = (const float*)d_in[11];
  const float* att_W2  = (const float*)d_in[12];
  const float* att_b2  = (const float*)d_in[13];
  const float* att_V   = (const float*)d_in[14];
  const float* att_bV  = (const float*)d_in[15];
  const float* fc_W    = (const float*)d_in[16];
  const float* fc_b    = (const float*)d_in[17];
  float* out = (float*)d_out;

  char* ws = (char*)d_ws;
  size_t o = 0;
  auto alloc = [&](size_t bytes) {
    char* p = ws + o;
    o = (o + bytes + 255) & ~(size_t)255;
    return p;
  };
  float*          Xe      = (float*)alloc((size_t)S_ * B_ * G4 * 4);
  float*          Xd      = (float*)alloc((size_t)T_ * B_ * G4 * 4);
  float*          enc_out = (float*)alloc((size_t)B_ * S_ * U_ * 4);
  unsigned char*  keys8   = (unsigned char*)alloc((size_t)B_ * S_ * U_);
  unsigned char*  eo8T    = (unsigned char*)alloc((size_t)B_ * U_ * S_);
  unsigned short* Hbf     = (unsigned short*)alloc((size_t)T_ * B_ * U_ * 2);
  unsigned short* fcWt    = (unsigned short*)alloc((size_t)V_ * U_ * 2);
  float*          h_state = (float*)alloc((size_t)B_ * U_ * 4);
  float*          c_state = (float*)alloc((size_t)B_ * U_ * 4);
  float*          rs_part = (float*)alloc((size_t)250 * 4096 * 4);
  float*          row_inv = (float*)alloc((size_t)4096 * 4);
  // tagged publication buffers (zeroed each launch for graph replay)
  size_t pub_off = o;
  u64* hpubE = (u64*)alloc((size_t)2 * 32 * 128 * 8);
  u64* hpub2 = (u64*)alloc((size_t)2 * 32 * 128 * 8);
  size_t pub_bytes = o - pub_off;
  // bf16 exp intermediate (262 MB) if workspace allows
  size_t expv_bytes = (size_t)B_ * T_ * V_ * 2;
  unsigned short* expv = nullptr;
  if (o + expv_bytes <= ws_size)
    expv = (unsigned short*)alloc(expv_bytes);

  (void)hipMemsetAsync(ws + pub_off, 0, pub_bytes, stream);
  hipLaunchKernelGGL(k_prep_x, dim3(1024), dim3(256), 0, stream,
                     src, tgt, enc_emb, enc_Wx, enc_b, dec_emb, dec_Wx, dec_b, Xe, Xd);
  hipLaunchKernelGGL(k_prep_fcw, dim3(2000), dim3(256), 0, stream, fc_W, fcWt);
  hipLaunchKernelGGL(k_encoder8, dim3(256), dim3(1024), 0, stream,
                     Xe, enc_Wh, enc_out, h_state, c_state, hpubE);
  hipLaunchKernelGGL(k_keys, dim3(512), dim3(256), 0, stream,
                     enc_out, att_W2, att_b2, keys8, eo8T);
  hipLaunchKernelGGL(k_decoder, dim3(256), dim3(1024), 0, stream,
                     Xd, dec_Wx, dec_Wh, att_W1, att_b1, att_V, att_bV,
                     keys8, eo8T, h_state, c_state, Hbf, hpub2);
  hipLaunchKernelGGL(k_fc, dim3(4000), dim3(256), 0, stream,
                     Hbf, fcWt, fc_b, out, expv, rs_part);
  hipLaunchKernelGGL(k_rowsum, dim3(16), dim3(256), 0, stream, rs_part, row_inv);
  if (expv)
    hipLaunchKernelGGL(k_norm_bf16, dim3(4096), dim3(256), 0, stream,
                       expv, out, row_inv);
  else
    hipLaunchKernelGGL(k_norm, dim3(2048), dim3(256), 0, stream,
                       (float4*)d_out, row_inv);
}

// Round 15
// 1331.366 us; speedup vs baseline: 1.3245x; 1.1428x over previous
//
#include <hip/hip_runtime.h>
#include <hip/hip_bf16.h>
#include <hip/hip_fp16.h>
#include <cstdint>
#include <cstddef>

#define B_ 32
#define S_ 128
#define T_ 128
#define E_ 128
#define U_ 256
#define V_ 32000
#define G4 1024          // 4*U
#define TV 4096000       // T_*V_

typedef __attribute__((ext_vector_type(8))) short short8_t;   // 8 bf16
typedef __attribute__((ext_vector_type(8))) unsigned short ushort8_t;
typedef __attribute__((ext_vector_type(4))) float f32x4;
typedef __attribute__((ext_vector_type(4))) unsigned uint4v;
typedef unsigned long long u64;

static __device__ __forceinline__ unsigned short f2bf(float x) {
  union { float f; unsigned int u; } v; v.f = x;
  unsigned int r = (v.u + 0x7fffu + ((v.u >> 16) & 1u)) >> 16;
  return (unsigned short)r;
}
static __device__ __forceinline__ float bf2f(unsigned short u) {
  return __uint_as_float(((unsigned)u) << 16);
}
static __device__ __forceinline__ float sigmoidf_(float x) {
  return 1.0f / (1.0f + __expf(-x));
}
static __device__ __forceinline__ float tanhf_(float x) {
  float e = __expf(2.0f * x);
  return 1.0f - 2.0f / (e + 1.0f);
}

// ---- e5m2 (truncated fp16) encode ----
static __device__ __forceinline__ unsigned int f2e5(float x) {
  __half h = __float2half(x);
  __half_raw hr = *(__half_raw*)&h;
  unsigned int u = hr.x;
  unsigned int r = (u + 0x7Fu + ((u >> 8) & 1u)) >> 8;   // RNE to 8 bits
  return r & 0xFFu;
}

// ---- packed fp16 helpers ----
static __device__ __forceinline__ unsigned pk2(float a, float b) {
  auto h = __builtin_amdgcn_cvt_pkrtz(a, b);
  return __builtin_bit_cast(unsigned, h);
}
#define SEL01 0x05000400u   // bytes -> half2(b0<<8, b1<<8)
#define SEL23 0x07000600u
static __device__ __forceinline__ unsigned e5pair(unsigned w, unsigned sel) {
  return __builtin_amdgcn_perm(w, 0u, sel);
}
static __device__ __forceinline__ float dot2(unsigned a, unsigned b, float c) {
  float d;
  asm("v_dot2_f32_f16 %0, %1, %2, %3" : "=v"(d) : "v"(a), "v"(b), "v"(c));
  return d;
}
static __device__ __forceinline__ unsigned pkadd(unsigned a, unsigned b) {
  unsigned d; asm("v_pk_add_f16 %0, %1, %2" : "=v"(d) : "v"(a), "v"(b)); return d;
}
static __device__ __forceinline__ unsigned pkmul(unsigned a, unsigned b) {
  unsigned d; asm("v_pk_mul_f16 %0, %1, %2" : "=v"(d) : "v"(a), "v"(b)); return d;
}
static __device__ __forceinline__ unsigned pkfma(unsigned a, unsigned b, unsigned c) {
  unsigned d; asm("v_pk_fma_f16 %0, %1, %2, %3" : "=v"(d) : "v"(a), "v"(b), "v"(c)); return d;
}
static __device__ __forceinline__ unsigned pkmax(unsigned a, unsigned b) {
  unsigned d; asm("v_pk_max_f16 %0, %1, %2" : "=v"(d) : "v"(a), "v"(b)); return d;
}
static __device__ __forceinline__ unsigned pkmin(unsigned a, unsigned b) {
  unsigned d; asm("v_pk_min_f16 %0, %1, %2" : "=v"(d) : "v"(a), "v"(b)); return d;
}

// ---- tagged agent-scope publication ----
static __device__ __forceinline__ void pub64u(u64* p, unsigned val, unsigned tag) {
  u64 v = ((u64)tag << 32) | (u64)val;
  __hip_atomic_store(p, v, __ATOMIC_RELAXED, __HIP_MEMORY_SCOPE_AGENT);
}
static __device__ __forceinline__ u64 ld64(const u64* p) {
  return __hip_atomic_load(p, __ATOMIC_RELAXED, __HIP_MEMORY_SCOPE_AGENT);
}

// ---------------------------------------------------------------------------
// K1: embedding gather + x@Wx + bias precompute for encoder and decoder.
// ---------------------------------------------------------------------------
__global__ __launch_bounds__(256) void k_prep_x(
    const int* __restrict__ src, const int* __restrict__ tgt,
    const float* __restrict__ enc_emb, const float* __restrict__ enc_Wx,
    const float* __restrict__ enc_b,
    const float* __restrict__ dec_emb, const float* __restrict__ dec_Wx,
    const float* __restrict__ dec_b,
    float* __restrict__ Xe, float* __restrict__ Xd)
{
  __shared__ float emb_l[8][E_];
  int wg = blockIdx.x;
  int tid = threadIdx.x;
  bool is_dec = (wg >= 512);
  int r0 = (is_dec ? (wg - 512) : wg) * 8;
  const float* emb  = is_dec ? dec_emb : enc_emb;
  const float* W    = is_dec ? (dec_Wx + (size_t)U_ * G4) : enc_Wx;
  const float* bias = is_dec ? dec_b : enc_b;
  float* Xout = is_dec ? Xd : Xe;

  for (int i = 0; i < 4; ++i) {
    int lin = i * 256 + tid;
    int rr = lin >> 7, k = lin & 127;
    int r = r0 + rr;               // r = step*32 + b
    int b = r & 31, st = r >> 5;
    int tok;
    if (is_dec) tok = tgt[b * T_ + (st > 0 ? st - 1 : 0)];
    else        tok = src[b * S_ + st];
    emb_l[rr][k] = emb[(size_t)tok * E_ + k];
  }
  __syncthreads();

  float acc[8][4];
  #pragma unroll
  for (int rr = 0; rr < 8; ++rr)
    #pragma unroll
    for (int cc = 0; cc < 4; ++cc) acc[rr][cc] = 0.f;

  for (int k = 0; k < E_; ++k) {
    float w0 = W[(size_t)k * G4 + tid];
    float w1 = W[(size_t)k * G4 + tid + 256];
    float w2 = W[(size_t)k * G4 + tid + 512];
    float w3 = W[(size_t)k * G4 + tid + 768];
    #pragma unroll
    for (int rr = 0; rr < 8; ++rr) {
      float e = emb_l[rr][k];
      acc[rr][0] += e * w0; acc[rr][1] += e * w1;
      acc[rr][2] += e * w2; acc[rr][3] += e * w3;
    }
  }
  #pragma unroll
  for (int rr = 0; rr < 8; ++rr) {
    int r = r0 + rr;
    #pragma unroll
    for (int cc = 0; cc < 4; ++cc) {
      int col = tid + cc * 256;
      Xout[(size_t)r * G4 + col] = acc[rr][cc] + bias[col];
    }
  }
}

// ---------------------------------------------------------------------------
// K2: transpose fc_W [256][32000] f32 -> fcWt [32000][256] bf16
// ---------------------------------------------------------------------------
__global__ __launch_bounds__(256) void k_prep_fcw(
    const float* __restrict__ fcW, unsigned short* __restrict__ fcWt)
{
  __shared__ float tile[64][65];
  int bid = blockIdx.x, tid = threadIdx.x;
  int n0 = (bid % 500) * 64, k0 = (bid / 500) * 64;
  for (int i = 0; i < 16; ++i) {
    int lin = i * 256 + tid;
    int k = lin >> 6, n = lin & 63;
    tile[k][n] = fcW[(size_t)(k0 + k) * V_ + n0 + n];
  }
  __syncthreads();
  for (int i = 0; i < 16; ++i) {
    int lin = i * 256 + tid;
    int n = lin >> 6, k = lin & 63;
    fcWt[(size_t)(n0 + n) * 256 + k0 + k] = f2bf(tile[k][n]);
  }
}

// ---------------------------------------------------------------------------
// K3: encoder LSTM, 8 WGs x 1024 threads per b.
// ---------------------------------------------------------------------------
__global__ __launch_bounds__(1024) void k_encoder8(
    const float* __restrict__ Xe, const float* __restrict__ Wh,
    float* __restrict__ enc_out, float* __restrict__ h_state,
    float* __restrict__ c_state, u64* __restrict__ hpubE /*[2][32][128]*/)
{
  __shared__ unsigned int WhU[64 * 128];   // [k4][c], 32KB
  __shared__ unsigned int h2[128];
  __shared__ float scr_z[8 * 128];

  int bid = blockIdx.x, tid = threadIdx.x;
  int b = bid & 31, g = bid >> 5;          // 8 WGs of b share an XCD

  for (int idx = tid; idx < 64 * 128; idx += 1024) {
    int k4 = idx >> 7, c = idx & 127;
    int gc = (c >> 5) * 256 + g * 32 + (c & 31);
    unsigned w = 0;
    #pragma unroll
    for (int i = 0; i < 4; ++i)
      w |= f2e5(Wh[(size_t)(4 * k4 + i) * G4 + gc]) << (8 * i);
    WhU[k4 * 128 + c] = w;
  }
  if (tid < 128) h2[tid] = 0u;
  float c_reg = 0.f, h_reg = 0.f;
  __syncthreads();

  for (int s = 0; s < S_; ++s) {
    float xe0 = 0.f, xe1 = 0.f, xe2 = 0.f, xe3 = 0.f;
    if (tid < 32) {
      const float* xe = Xe + (size_t)(s * B_ + b) * G4 + g * 32 + tid;
      xe0 = xe[0]; xe1 = xe[256]; xe2 = xe[512]; xe3 = xe[768];
    }
    // z phase (c = tid&127, k8 = tid>>7)
    {
      int c = tid & 127, k8 = tid >> 7;
      const unsigned* wp = &WhU[(k8 * 8) * 128 + c];
      const unsigned* hh = &h2[k8 * 16];
      float z0 = 0.f, z1 = 0.f;
      #pragma unroll
      for (int j = 0; j < 8; ++j) {
        unsigned w = wp[j * 128];
        z0 = dot2(e5pair(w, SEL01), hh[2 * j], z0);
        z1 = dot2(e5pair(w, SEL23), hh[2 * j + 1], z1);
      }
      scr_z[k8 * 128 + c] = z0 + z1;
    }
    __syncthreads();
    // pointwise + publish + poll-next
    if (tid < 32) {
      int r = tid, gc = g * 32 + r;
      float z[4] = {xe0, xe1, xe2, xe3};
      #pragma unroll
      for (int q = 0; q < 4; ++q) {
        int c = q * 32 + r;
        #pragma unroll
        for (int k8 = 0; k8 < 8; ++k8) z[q] += scr_z[k8 * 128 + c];
      }
      float c = sigmoidf_(z[1]) * c_reg + sigmoidf_(z[0]) * tanhf_(z[2]);
      c_reg = c;
      float h = sigmoidf_(z[3]) * tanhf_(c);
      h_reg = h;
      enc_out[((size_t)(b * S_ + s)) * U_ + gc] = h;
      if (s < S_ - 1) {
        float hx = __shfl_xor(h, 1);
        if (!(r & 1))
          pub64u(&hpubE[((size_t)((s + 1) & 1) * 32 + b) * 128 + g * 16 + (r >> 1)],
                 pk2(h, hx), (unsigned)(s + 1));
      }
    }
    if (s < S_ - 1 && tid < 128) {
      const u64* p = &hpubE[((size_t)((s + 1) & 1) * 32 + b) * 128 + tid];
      u64 v = ld64(p);
      while ((unsigned)(v >> 32) < (unsigned)(s + 1)) { __builtin_amdgcn_s_sleep(1); v = ld64(p); }
      h2[tid] = (unsigned)v;
    }
    __syncthreads();
  }
  if (tid < 32) {
    h_state[b * U_ + g * 32 + tid] = h_reg;
    c_state[b * U_ + g * 32 + tid] = c_reg;
  }
}

// ---------------------------------------------------------------------------
// K4: keys8 = e5m2(enc_out @ att_W2 + b2); eo8T = e5m2(enc_out)^T.
// ---------------------------------------------------------------------------
__global__ __launch_bounds__(256) void k_keys(
    const float* __restrict__ enc_out, const float* __restrict__ W2,
    const float* __restrict__ b2,
    unsigned char* __restrict__ keys8, unsigned char* __restrict__ eo8T)
{
  __shared__ float x_l[8][U_];
  int wg = blockIdx.x, tid = threadIdx.x;
  int r0 = wg * 8;
  for (int i = 0; i < 8; ++i) x_l[i][tid] = enc_out[(size_t)(r0 + i) * U_ + tid];
  __syncthreads();
  float acc[8];
  #pragma unroll
  for (int rr = 0; rr < 8; ++rr) acc[rr] = 0.f;
  for (int k = 0; k < U_; ++k) {
    float w = W2[(size_t)k * U_ + tid];
    #pragma unroll
    for (int rr = 0; rr < 8; ++rr) acc[rr] += x_l[rr][k] * w;
  }
  float bb = b2[tid];
  #pragma unroll
  for (int rr = 0; rr < 8; ++rr) {
    int r = r0 + rr;                       // r = b*128 + s
    keys8[(size_t)r * U_ + tid] = (unsigned char)f2e5(acc[rr] + bb);
    int bI = r >> 7, sI = r & 127;
    eo8T[((size_t)bI * U_ + tid) * S_ + sI] = (unsigned char)f2e5(x_l[rr][tid]);
  }
}

// ---------------------------------------------------------------------------
// K5: decoder (proven 760us structure).
// ---------------------------------------------------------------------------
__global__ __launch_bounds__(1024) void k_decoder(
    const float* __restrict__ Xd, const float* __restrict__ dec_Wx,
    const float* __restrict__ Wh,
    const float* __restrict__ W1, const float* __restrict__ b1,
    const float* __restrict__ attV, const float* __restrict__ attbV,
    const unsigned char* __restrict__ keys8, const unsigned char* __restrict__ eo8T,
    const float* __restrict__ h0, const float* __restrict__ c0,
    unsigned short* __restrict__ Hbf,
    u64* __restrict__ hpub2 /*[2][32][128]*/)
{
  __shared__ unsigned int WxU[64 * 128];   // [k4][c] e5m2 ctx weights, 32KB
  __shared__ unsigned int WhU[64 * 128];   // [k4][c] e5m2 h weights, 32KB
  __shared__ unsigned int W1U[64 * 256];   // [k4][u] full W1, 64KB
  __shared__ float scr_q[4 * 256];         // q k-quarter partials
  __shared__ float scr_c[4 * 256];         // ctx s-quarter partials (unnormalized)
  __shared__ float scr_z[8 * 128];         // z partials
  __shared__ unsigned int q2[160];         // half2 q, oct-padded 8x20
  __shared__ unsigned int aV2[160];
  __shared__ unsigned int h2[128];
  __shared__ unsigned int ctx2[128];       // unnormalized ctx pairs
  __shared__ unsigned int esc2[64];
  __shared__ float escw[16];
  __shared__ float b1_l[256];

  int bid = blockIdx.x, tid = threadIdx.x;
  int b = bid & 31, g = bid >> 5;          // 8 WGs of b on one XCD
  int lane = tid & 63, wid = tid >> 6;

  // ---- one-time staging ----
  for (int idx = tid; idx < 64 * 128; idx += 1024) {   // Wx(ctx rows)/Wh slices
    int k4 = idx >> 7, c = idx & 127;
    int gc = (c >> 5) * 256 + g * 32 + (c & 31);
    unsigned wx = 0, wh = 0;
    #pragma unroll
    for (int i = 0; i < 4; ++i) {
      int k = 4 * k4 + i;
      wx |= f2e5(dec_Wx[(size_t)k * G4 + gc]) << (8 * i);
      wh |= f2e5(Wh[(size_t)k * G4 + gc]) << (8 * i);
    }
    WxU[k4 * 128 + c] = wx;
    WhU[k4 * 128 + c] = wh;
  }
  for (int idx = tid; idx < 64 * 256; idx += 1024) {   // full W1
    int k4 = idx >> 8, u = idx & 255;
    unsigned w = 0;
    #pragma unroll
    for (int i = 0; i < 4; ++i)
      w |= f2e5(W1[(size_t)(4 * k4 + i) * U_ + u]) << (8 * i);
    W1U[k4 * 256 + u] = w;
  }
  if (tid < 128) {
    int p = tid;                           // pair index
    aV2[(p >> 4) * 20 + (p & 15)] = pk2(attV[2 * p], attV[2 * p + 1]);
  }
  if (tid < 256) b1_l[tid] = b1[tid];
  float bV = attbV[0];
  float c_reg = 0.f, h_reg = 0.f;
  if (tid < 32) {
    h_reg = h0[b * U_ + g * 32 + tid];
    c_reg = c0[b * U_ + g * 32 + tid];
  }
  __syncthreads();

  // ---- initial publish + initial poll (tag 1, parity 0) ----
  if (tid < 32) {
    float hx = __shfl_xor(h_reg, 1);
    if (!(tid & 1))
      pub64u(&hpub2[((size_t)0 * 32 + b) * 128 + g * 16 + (tid >> 1)], pk2(h_reg, hx), 1u);
  }
  if (tid < 128) {
    const u64* hp = &hpub2[((size_t)0 * 32 + b) * 128 + tid];
    u64 vh = ld64(hp);
    while ((unsigned)(vh >> 32) < 1u) { __builtin_amdgcn_s_sleep(1); vh = ld64(hp); }
    h2[tid] = (unsigned)vh;
  }
  __syncthreads();

  const unsigned NEG1 = pk2(-1.f, -1.f), POS1 = pk2(1.f, 1.f);
  const unsigned C1 = pk2(-0.333333333f, -0.333333333f);
  const unsigned C2 = pk2(0.133333333f, 0.133333333f);
  const unsigned C3 = pk2(-0.053968254f, -0.053968254f);

  const unsigned char* kb = keys8 + (size_t)b * S_ * U_;
  const unsigned char* eb = eo8T + (size_t)b * U_ * S_;

  for (int t = 0; t < T_; ++t) {
    // ---- Xd prefetch ----
    float xd0 = 0.f, xd1 = 0.f, xd2 = 0.f, xd3 = 0.f;
    if (tid < 32) {
      const float* xd = Xd + (size_t)(t * B_ + b) * G4 + g * 32 + tid;
      xd0 = xd[0]; xd1 = xd[256]; xd2 = xd[512]; xd3 = xd[768];
    }

    // ---- P2: issue key/eo loads; q k-quarters over all 1024 threads ----
    int sI = tid >> 3, uo = tid & 7;          // scores mapping (P3)
    int uI = tid & 255, sq = tid >> 8;        // ctx mapping (P4)
    uint4v kA, kB, eA, eB;
    {
      const uint4v* kp = (const uint4v*)(kb + (size_t)sI * U_ + uo * 32);
      kA = kp[0]; kB = kp[1];
      const uint4v* ep = (const uint4v*)(eb + (size_t)uI * S_ + sq * 32);
      eA = ep[0]; eB = ep[1];
    }
    {
      int c = tid & 255, kq = tid >> 8;
      const unsigned* wp = &W1U[(kq * 16) * 256 + c];
      const unsigned* hh = &h2[kq * 32];
      float qa = 0.f, qb = 0.f;
      #pragma unroll
      for (int j = 0; j < 16; ++j) {
        unsigned w = wp[j * 256];
        qa = dot2(e5pair(w, SEL01), hh[2 * j], qa);
        qb = dot2(e5pair(w, SEL23), hh[2 * j + 1], qb);
      }
      scr_q[kq * 256 + c] = qa + qb;
    }
    __syncthreads();

    // ---- P2b: merge q quarters -> half2 pairs ----
    if (tid < 128) {
      int u0 = 2 * tid;
      float q0 = scr_q[u0] + scr_q[256 + u0] + scr_q[512 + u0] + scr_q[768 + u0] + b1_l[u0];
      float q1 = scr_q[u0 + 1] + scr_q[256 + u0 + 1] + scr_q[512 + u0 + 1] + scr_q[768 + u0 + 1] + b1_l[u0 + 1];
      q2[(tid >> 4) * 20 + (tid & 15)] = pk2(q0, q1);
    }
    __syncthreads();

    // ---- P3: scores (s = tid>>3, u-oct = tid&7, 32 u each) ----
    {
      unsigned kw[8] = {kA.x, kA.y, kA.z, kA.w, kB.x, kB.y, kB.z, kB.w};
      const unsigned* qq = &q2[uo * 20];
      const unsigned* vv = &aV2[uo * 20];
      float a0 = 0.f, a1 = 0.f;
      #pragma unroll
      for (int j = 0; j < 8; ++j) {
        unsigned w = kw[j];
        unsigned x0 = pkadd(e5pair(w, SEL01), qq[2 * j]);
        unsigned x1 = pkadd(e5pair(w, SEL23), qq[2 * j + 1]);
        x0 = pkmin(pkmax(x0, NEG1), POS1);
        x1 = pkmin(pkmax(x1, NEG1), POS1);
        unsigned s0_ = pkmul(x0, x0), s1_ = pkmul(x1, x1);
        unsigned t0 = pkfma(s0_, C3, C2), t1 = pkfma(s1_, C3, C2);
        t0 = pkfma(s0_, t0, C1); t1 = pkfma(s1_, t1, C1);
        unsigned th0 = pkfma(pkmul(x0, s0_), t0, x0);
        unsigned th1 = pkfma(pkmul(x1, s1_), t1, x1);
        a0 = dot2(th0, vv[2 * j], a0);
        a1 = dot2(th1, vv[2 * j + 1], a1);
      }
      float a = a0 + a1;
      a += __shfl_xor(a, 1); a += __shfl_xor(a, 2); a += __shfl_xor(a, 4);
      float ea = __expf(a + bV);
      float ep = __shfl_xor(ea, 8);            // s^1's value
      if (uo == 0 && !(sI & 1)) esc2[sI >> 1] = pk2(ea, ep);
      float dsum = ea;                         // sum 8 distinct s in wave
      dsum += __shfl_xor(dsum, 8); dsum += __shfl_xor(dsum, 16); dsum += __shfl_xor(dsum, 32);
      if (lane == 0) escw[wid] = dsum;
    }
    __syncthreads();

    // ---- P4: ctx partials (u = tid&255, s-quarter = tid>>8, 32 s each) ----
    {
      unsigned ewv[8] = {eA.x, eA.y, eA.z, eA.w, eB.x, eB.y, eB.z, eB.w};
      const unsigned* e2 = &esc2[sq * 16];
      float c0a = 0.f, c1a = 0.f;
      #pragma unroll
      for (int j = 0; j < 8; ++j) {
        unsigned w = ewv[j];
        c0a = dot2(e5pair(w, SEL01), e2[2 * j], c0a);
        c1a = dot2(e5pair(w, SEL23), e2[2 * j + 1], c1a);
      }
      scr_c[sq * 256 + uI] = c0a + c1a;
    }
    __syncthreads();

    // ---- P4b: unnormalized ctx pairs ----
    if (tid < 128) {
      int u0 = 2 * tid;
      float ca = scr_c[u0] + scr_c[256 + u0] + scr_c[512 + u0] + scr_c[768 + u0];
      float cb = scr_c[u0 + 1] + scr_c[256 + u0 + 1] + scr_c[512 + u0 + 1] + scr_c[768 + u0 + 1];
      ctx2[tid] = pk2(ca, cb);
    }
    __syncthreads();

    // ---- P5: z = z_h + z_ctx * dinv (c = tid&127, k-8th = tid>>7) ----
    {
      float d = ((escw[0] + escw[1]) + (escw[2] + escw[3])) +
                ((escw[4] + escw[5]) + (escw[6] + escw[7])) +
                ((escw[8] + escw[9]) + (escw[10] + escw[11])) +
                ((escw[12] + escw[13]) + (escw[14] + escw[15]));
      float dinv = 1.0f / d;
      int c = tid & 127, k8 = tid >> 7;
      const unsigned* wxp = &WxU[(k8 * 8) * 128 + c];
      const unsigned* whp = &WhU[(k8 * 8) * 128 + c];
      const unsigned* cc = &ctx2[k8 * 16];
      const unsigned* hh = &h2[k8 * 16];
      float zx0 = 0.f, zx1 = 0.f, zh0 = 0.f, zh1 = 0.f;
      #pragma unroll
      for (int j = 0; j < 8; ++j) {
        unsigned wx = wxp[j * 128], wh = whp[j * 128];
        zx0 = dot2(e5pair(wx, SEL01), cc[2 * j], zx0);
        zx1 = dot2(e5pair(wx, SEL23), cc[2 * j + 1], zx1);
        zh0 = dot2(e5pair(wh, SEL01), hh[2 * j], zh0);
        zh1 = dot2(e5pair(wh, SEL23), hh[2 * j + 1], zh1);
      }
      scr_z[k8 * 128 + c] = (zh0 + zh1) + (zx0 + zx1) * dinv;
    }
    __syncthreads();

    // ---- P6: pointwise (32 lanes) + h publish + poll-next ----
    if (tid < 32) {
      int r = tid, gc = g * 32 + r;
      float z[4] = {xd0, xd1, xd2, xd3};
      #pragma unroll
      for (int q = 0; q < 4; ++q) {
        int c = q * 32 + r;
        #pragma unroll
        for (int k8 = 0; k8 < 8; ++k8) z[q] += scr_z[k8 * 128 + c];
      }
      float c = sigmoidf_(z[1]) * c_reg + sigmoidf_(z[0]) * tanhf_(z[2]);
      c_reg = c;
      float h = sigmoidf_(z[3]) * tanhf_(c);
      h_reg = h;
      Hbf[(size_t)(t * B_ + b) * U_ + gc] = f2bf(h);
      if (t < T_ - 1) {
        int par1 = (t + 1) & 1;
        float hx = __shfl_xor(h, 1);
        if (!(r & 1))
          pub64u(&hpub2[((size_t)par1 * 32 + b) * 128 + g * 16 + (r >> 1)],
                 pk2(h, hx), (unsigned)(t + 2));
      }
    }
    if (t < T_ - 1 && tid < 128) {
      int par1 = (t + 1) & 1;
      unsigned tag2 = (unsigned)(t + 2);
      const u64* hp = &hpub2[((size_t)par1 * 32 + b) * 128 + tid];
      u64 vh = ld64(hp);
      while ((unsigned)(vh >> 32) < tag2) { __builtin_amdgcn_s_sleep(1); vh = ld64(hp); }
      h2[tid] = (unsigned)vh;
    }
    __syncthreads();
  }
}

// ---------------------------------------------------------------------------
// K6: fc GEMM (MFMA bf16) + exp epilogue + row-sum partials (R10 verbatim).
// ---------------------------------------------------------------------------
__global__ __launch_bounds__(256) void k_fc(
    const unsigned short* __restrict__ Hbf, const unsigned short* __restrict__ fcWt,
    const float* __restrict__ fcb, float* __restrict__ out,
    unsigned short* __restrict__ expv,
    float* __restrict__ rs_part)
{
  __shared__ uint4v Al[128 * 8];
  __shared__ uint4v Bl[128 * 8];
  __shared__ float rsum_l[128][2];

  int bid = blockIdx.x, tid = threadIdx.x;
  int nt = bid >> 5, mt = bid & 31;
  int m0 = mt * 128, n0 = nt * 128;
  int lane = tid & 63, wave = tid >> 6;
  int wm = (wave >> 1) * 64, wn = (wave & 1) * 64;
  int g = lane >> 4, r15 = lane & 15;

  f32x4 acc[4][4];
  f32x4 zero = {0.f, 0.f, 0.f, 0.f};
  #pragma unroll
  for (int mi = 0; mi < 4; ++mi)
    #pragma unroll
    for (int ni = 0; ni < 4; ++ni) acc[mi][ni] = zero;

  const unsigned short* Ag = Hbf  + (size_t)m0 * 256;
  const unsigned short* Bg = fcWt + (size_t)n0 * 256;

  for (int kt = 0; kt < 4; ++kt) {
    int kk = kt * 64;
    #pragma unroll
    for (int blk = 0; blk < 4; ++blk) {
      int lin = blk * 256 + tid;
      int row = lin >> 3, kq = lin & 7;
      Al[row * 8 + (kq ^ (row & 7))] = *(const uint4v*)(Ag + (size_t)row * 256 + kk + kq * 8);
      Bl[row * 8 + (kq ^ (row & 7))] = *(const uint4v*)(Bg + (size_t)row * 256 + kk + kq * 8);
    }
    __syncthreads();
    #pragma unroll
    for (int kk2 = 0; kk2 < 2; ++kk2) {
      short8_t a[4], bfr[4];
      #pragma unroll
      for (int mi = 0; mi < 4; ++mi) {
        int row = wm + mi * 16 + r15;
        a[mi] = *(const short8_t*)&Al[row * 8 + ((kk2 * 4 + g) ^ (row & 7))];
      }
      #pragma unroll
      for (int ni = 0; ni < 4; ++ni) {
        int row = wn + ni * 16 + r15;
        bfr[ni] = *(const short8_t*)&Bl[row * 8 + ((kk2 * 4 + g) ^ (row & 7))];
      }
      #pragma unroll
      for (int mi = 0; mi < 4; ++mi)
        #pragma unroll
        for (int ni = 0; ni < 4; ++ni)
          acc[mi][ni] = __builtin_amdgcn_mfma_f32_16x16x32_bf16(a[mi], bfr[ni], acc[mi][ni], 0, 0, 0);
    }
    __syncthreads();
  }

  float fcb_l[4];
  #pragma unroll
  for (int ni = 0; ni < 4; ++ni) fcb_l[ni] = fcb[n0 + wn + ni * 16 + r15];

  #pragma unroll
  for (int mi = 0; mi < 4; ++mi) {
    #pragma unroll
    for (int jj = 0; jj < 4; ++jj) {
      int rloc = wm + mi * 16 + g * 4 + jj;
      int grow = m0 + rloc;                     // = t*32 + b
      int bb = grow & 31, tt = grow >> 5;
      size_t obase = (size_t)bb * TV + (size_t)tt * V_;
      float s = 0.f;
      if (expv) {
        #pragma unroll
        for (int ni = 0; ni < 4; ++ni) {
          float v = __expf(acc[mi][ni][jj] + fcb_l[ni]);
          unsigned short us = f2bf(v);
          expv[obase + n0 + wn + ni * 16 + r15] = us;
          s += bf2f(us);
        }
      } else {
        #pragma unroll
        for (int ni = 0; ni < 4; ++ni) {
          float v = __expf(acc[mi][ni][jj] + fcb_l[ni]);
          out[obase + n0 + wn + ni * 16 + r15] = v;
          s += v;
        }
      }
      s += __shfl_xor(s, 1); s += __shfl_xor(s, 2);
      s += __shfl_xor(s, 4); s += __shfl_xor(s, 8);
      if (r15 == 0) rsum_l[rloc][wave & 1] = s;
    }
  }
  __syncthreads();
  if (tid < 128)
    rs_part[(size_t)nt * 4096 + m0 + tid] = rsum_l[tid][0] + rsum_l[tid][1];
}

// ---------------------------------------------------------------------------
// K7: reduce partial row sums -> 1/sum per GEMM row
// ---------------------------------------------------------------------------
__global__ __launch_bounds__(256) void k_rowsum(
    const float* __restrict__ rs_part, float* __restrict__ row_inv)
{
  int gidx = blockIdx.x * 256 + threadIdx.x;
  float s = 0.f;
  for (int nt = 0; nt < 250; ++nt) s += rs_part[(size_t)nt * 4096 + gidx];
  row_inv[gidx] = 1.0f / s;
}

// ---------------------------------------------------------------------------
// K8a: normalize from bf16 exp -> fp32 out
// ---------------------------------------------------------------------------
__global__ __launch_bounds__(256) void k_norm_bf16(
    const unsigned short* __restrict__ expv, float* __restrict__ out,
    const float* __restrict__ row_inv)
{
  const long total = 16384000;   // 131072000 / 8
  long stride = (long)gridDim.x * 256;
  for (long i = (long)blockIdx.x * 256 + threadIdx.x; i < total; i += stride) {
    long flat = i * 8;
    int bb = (int)(flat / TV);
    int rem = (int)(flat % TV);
    int tt = rem / V_;
    float sc = row_inv[tt * 32 + bb];
    ushort8_t v = *(const ushort8_t*)&expv[flat];
    float4 o0, o1;
    o0.x = bf2f(v[0]) * sc; o0.y = bf2f(v[1]) * sc;
    o0.z = bf2f(v[2]) * sc; o0.w = bf2f(v[3]) * sc;
    o1.x = bf2f(v[4]) * sc; o1.y = bf2f(v[5]) * sc;
    o1.z = bf2f(v[6]) * sc; o1.w = bf2f(v[7]) * sc;
    *(float4*)&out[flat] = o0;
    *(float4*)&out[flat + 4] = o1;
  }
}

// ---------------------------------------------------------------------------
// K8b: fallback in-place fp32 normalize
// ---------------------------------------------------------------------------
__global__ __launch_bounds__(256) void k_norm(
    float4* __restrict__ out4, const float* __restrict__ row_inv)
{
  const long total = 32768000;
  long stride = (long)gridDim.x * 256;
  for (long i = (long)blockIdx.x * 256 + threadIdx.x; i < total; i += stride) {
    long flat = i * 4;
    int bb = (int)(flat / TV);
    int rem = (int)(flat % TV);
    int tt = rem / V_;
    float sc = row_inv[tt * 32 + bb];
    float4 v = out4[i];
    v.x *= sc; v.y *= sc; v.z *= sc; v.w *= sc;
    out4[i] = v;
  }
}

// ---------------------------------------------------------------------------
extern "C" void kernel_launch(void* const* d_in, const int* in_sizes, int n_in,
                              void* d_out, int out_size, void* d_ws, size_t ws_size,
                              hipStream_t stream) {
  (void)in_sizes; (void)n_in; (void)out_size;
  const int*   src     = (const int*)d_in[0];
  const int*   tgt     = (const int*)d_in[1];
  const float* enc_emb = (const float*)d_in[2];
  const float* enc_Wx  = (const float*)d_in[3];
  const float* enc_Wh  = (const float*)d_in[4];
  const float* enc_b   = (const float*)d_in[5];
  const float* dec_emb = (const float*)d_in[6];
  const float* dec_Wx  = (const float*)d_in[7];
  const float* dec_Wh  = (const float*)d_in[8];
  const float* dec_b   = (const float*)d_in[9];
  const float* att_W1  = (const float*)d_in[10];
  const float* att_b1  = (const float*)d_in[11];
  const float* att_W2  = (const float*)d_in[12];
  const float* att_b2  = (const float*)d_in[13];
  const float* att_V   = (const float*)d_in[14];
  const float* att_bV  = (const float*)d_in[15];
  const float* fc_W    = (const float*)d_in[16];
  const float* fc_b    = (const float*)d_in[17];
  float* out = (float*)d_out;

  char* ws = (char*)d_ws;
  size_t o = 0;
  auto alloc = [&](size_t bytes) {
    char* p = ws + o;
    o = (o + bytes + 255) & ~(size_t)255;
    return p;
  };
  float*          Xe      = (float*)alloc((size_t)S_ * B_ * G4 * 4);
  float*          Xd      = (float*)alloc((size_t)T_ * B_ * G4 * 4);
  float*          enc_out = (float*)alloc((size_t)B_ * S_ * U_ * 4);
  unsigned char*  keys8   = (unsigned char*)alloc((size_t)B_ * S_ * U_);
  unsigned char*  eo8T    = (unsigned char*)alloc((size_t)B_ * U_ * S_);
  unsigned short* Hbf     = (unsigned short*)alloc((size_t)T_ * B_ * U_ * 2);
  unsigned short* fcWt    = (unsigned short*)alloc((size_t)V_ * U_ * 2);
  float*          h_state = (float*)alloc((size_t)B_ * U_ * 4);
  float*          c_state = (float*)alloc((size_t)B_ * U_ * 4);
  float*          rs_part = (float*)alloc((size_t)250 * 4096 * 4);
  float*          row_inv = (float*)alloc((size_t)4096 * 4);
  // tagged publication buffers (zeroed each launch for graph replay)
  size_t pub_off = o;
  u64* hpubE = (u64*)alloc((size_t)2 * 32 * 128 * 8);
  u64* hpub2 = (u64*)alloc((size_t)2 * 32 * 128 * 8);
  size_t pub_bytes = o - pub_off;
  // bf16 exp intermediate (262 MB) if workspace allows
  size_t expv_bytes = (size_t)B_ * T_ * V_ * 2;
  unsigned short* expv = nullptr;
  if (o + expv_bytes <= ws_size)
    expv = (unsigned short*)alloc(expv_bytes);

  (void)hipMemsetAsync(ws + pub_off, 0, pub_bytes, stream);
  hipLaunchKernelGGL(k_prep_x, dim3(1024), dim3(256), 0, stream,
                     src, tgt, enc_emb, enc_Wx, enc_b, dec_emb, dec_Wx, dec_b, Xe, Xd);
  hipLaunchKernelGGL(k_prep_fcw, dim3(2000), dim3(256), 0, stream, fc_W, fcWt);
  hipLaunchKernelGGL(k_encoder8, dim3(256), dim3(1024), 0, stream,
                     Xe, enc_Wh, enc_out, h_state, c_state, hpubE);
  hipLaunchKernelGGL(k_keys, dim3(512), dim3(256), 0, stream,
                     enc_out, att_W2, att_b2, keys8, eo8T);
  hipLaunchKernelGGL(k_decoder, dim3(256), dim3(1024), 0, stream,
                     Xd, dec_Wx, dec_Wh, att_W1, att_b1, att_V, att_bV,
                     keys8, eo8T, h_state, c_state, Hbf, hpub2);
  hipLaunchKernelGGL(k_fc, dim3(8000), dim3(256), 0, stream,
                     Hbf, fcWt, fc_b, out, expv, rs_part);
  hipLaunchKernelGGL(k_rowsum, dim3(16), dim3(256), 0, stream, rs_part, row_inv);
  if (expv)
    hipLaunchKernelGGL(k_norm_bf16, dim3(4096), dim3(256), 0, stream,
                       expv, out, row_inv);
  else
    hipLaunchKernelGGL(k_norm, dim3(2048), dim3(256), 0, stream,
                       (float4*)d_out, row_inv);
}